// Round 5
// baseline (412.334 us; speedup 1.0000x reference)
//
#include <hip/hip_runtime.h>
#include <cstddef>
#include <cstdint>

#define RR 16384   // B*N rows
#define CC 256
#define NN 2048

typedef __attribute__((ext_vector_type(8))) _Float16 h8;
typedef __attribute__((ext_vector_type(4))) float float4v;
typedef unsigned short u16;

__device__ inline float h2f(u16 u) {
  return (float)__builtin_bit_cast(_Float16, u);
}
__device__ inline u16 f2h(float f) {
  return __builtin_bit_cast(u16, (_Float16)f);
}

// ---------------------------------------------------------------------------
// LayerNorm -> split f16 [hi(256) | lo(256)] per row.
__global__ __launch_bounds__(256) void ln_split(const float* __restrict__ x,
    const float* __restrict__ g, const float* __restrict__ b,
    u16* __restrict__ out) {
  const int wave = threadIdx.x >> 6, lane = threadIdx.x & 63;
  const int row = (blockIdx.x << 2) + wave;
  const float4 v = ((const float4*)(x + (size_t)row * CC))[lane];
  float s1 = v.x + v.y + v.z + v.w;
  float s2 = v.x * v.x + v.y * v.y + v.z * v.z + v.w * v.w;
#pragma unroll
  for (int o = 32; o > 0; o >>= 1) {
    s1 += __shfl_xor(s1, o);
    s2 += __shfl_xor(s2, o);
  }
  const float mu = s1 * (1.0f / CC);
  const float var = s2 * (1.0f / CC) - mu * mu;
  const float rs = 1.0f / sqrtf(var + 1e-5f);
  const float4 gg = ((const float4*)g)[lane];
  const float4 bb = ((const float4*)b)[lane];
  float o4[4];
  o4[0] = (v.x - mu) * rs * gg.x + bb.x;
  o4[1] = (v.y - mu) * rs * gg.y + bb.y;
  o4[2] = (v.z - mu) * rs * gg.z + bb.z;
  o4[3] = (v.w - mu) * rs * gg.w + bb.w;
  ushort4 hi, lo;
  hi.x = f2h(o4[0]); lo.x = f2h(o4[0] - h2f(hi.x));
  hi.y = f2h(o4[1]); lo.y = f2h(o4[1] - h2f(hi.y));
  hi.z = f2h(o4[2]); lo.z = f2h(o4[2] - h2f(hi.z));
  hi.w = f2h(o4[3]); lo.w = f2h(o4[3] - h2f(hi.w));
  *(ushort4*)(out + (size_t)row * 512 + (lane << 2)) = hi;
  *(ushort4*)(out + (size_t)row * 512 + 256 + (lane << 2)) = lo;
}

// ---------------------------------------------------------------------------
// All weight splits in ONE dispatch (2304 blocks):
//  [0,768):    wq/wk/wv -> Wqkv 4-term rows 0/256/512
//  [768,1024): wo       -> wo2 4-term
//  [1024,2048): w1      -> w12 4-term
//  [2048,3072): w2      -> w22 2-term (K=1024)
__global__ __launch_bounds__(256) void split_all(const float* __restrict__ wq,
    const float* __restrict__ wk, const float* __restrict__ wv,
    const float* __restrict__ wo, const float* __restrict__ w1,
    const float* __restrict__ w2, u16* __restrict__ Wqkv,
    u16* __restrict__ wo2, u16* __restrict__ w12, u16* __restrict__ w22) {
  const int bid = blockIdx.x;
  if (bid < 1024) {  // 4-term splits, K=256
    const float* W; u16* D; int rowoff; int li;
    if (bid < 768) {
      W = (bid < 256) ? wq : (bid < 512) ? wk : wv;
      D = Wqkv; rowoff = (bid >> 8) << 8;
      li = (bid & 255) * 256 + threadIdx.x;
    } else {
      W = wo; D = wo2; rowoff = 0;
      li = (bid - 768) * 256 + threadIdx.x;
    }
    const int o = li >> 8, k = li & 255;
    const float w = W[li];
    const u16 h1 = f2h(w);
    const u16 h2 = f2h(w - h2f(h1));
    u16* base = D + (size_t)(o + rowoff) * 1024;
    base[k] = h1; base[256 + k] = h1; base[512 + k] = h2; base[768 + k] = h2;
  } else if (bid < 2048) {  // w1 4-term
    const int li = (bid - 1024) * 256 + threadIdx.x;
    const int o = li >> 8, k = li & 255;
    const float w = w1[li];
    const u16 h1 = f2h(w);
    const u16 h2 = f2h(w - h2f(h1));
    u16* base = w12 + (size_t)o * 1024;
    base[k] = h1; base[256 + k] = h1; base[512 + k] = h2; base[768 + k] = h2;
  } else {  // w2 2-term, K=1024
    const int li = (bid - 2048) * 256 + threadIdx.x;
    const int o = li >> 10, k = li & 1023;
    const float w = w2[li];
    const u16 h1 = f2h(w);
    const u16 h2 = f2h(w - h2f(h1));
    u16* base = w22 + (size_t)o * 2048;
    base[k] = h1; base[1024 + k] = h2;
  }
}

// ---------------------------------------------------------------------------
// MFMA f16 GEMM: Y[r,o] = sum_{k'} A[r, k' mod AW] * W2[o, k']  (+resid)
// Tile BM x BN, BK=64, 4 waves (WMxWN), mfma_f32_16x16x32_f16.
// T2 LDS swizzle both-sides; T1 XCD-aware block swizzle (nwg % 8 == 0).
// STATS: fused BN pass-1 — per-column partial sum/sumsq per row-panel,
// written to p1/p2[by*O + col]. Requires resid == nullptr semantics (acc only).
template <int BM, int BN, int WM, int WN, int STATS>
__global__ __launch_bounds__(256) void gemm_sp(
    const u16* __restrict__ A, int AW,
    const u16* __restrict__ W2, int K2,
    const float* __restrict__ resid, float* __restrict__ Y, int O,
    float* __restrict__ p1, float* __restrict__ p2) {
  constexpr int FM = BM / (WM * 16);
  constexpr int FN = BN / (WN * 16);
  __shared__ __align__(16) u16 As[BM * 64];
  __shared__ __align__(16) u16 Bs[BN * 64];
  const int tid = threadIdx.x;
  const int lane = tid & 63, wid = tid >> 6;
  const int wr = wid / WN, wc = wid % WN;
  // XCD-aware swizzle: contiguous chunk of tiles per XCD (row-panel reuse).
  const int gx = gridDim.x;
  const int lid = blockIdx.y * gx + blockIdx.x;
  const int chunk = (gx * gridDim.y) >> 3;
  const int nid = (lid & 7) * chunk + (lid >> 3);
  const int bx = nid % gx, by = nid / gx;
  const int r0 = by * BM, o0 = bx * BN;
  const int lrow = tid >> 3;                             // 0..31
  const int lce = ((tid & 7) ^ ((tid >> 3) & 7)) << 3;   // swizzled src chunk
  float4v acc[FM][FN] = {};
  int kA = 0;
  for (int k0 = 0; k0 < K2; k0 += 64) {
#pragma unroll
    for (int i = 0; i < BM / 32; ++i) {
      const u16* srcA = A + (size_t)(r0 + i * 32 + lrow) * AW + kA + lce;
      __builtin_amdgcn_global_load_lds(
          (const __attribute__((address_space(1))) void*)srcA,
          (__attribute__((address_space(3))) void*)&As[(i * 256 + (wid << 6)) * 8],
          16, 0, 0);
    }
#pragma unroll
    for (int i = 0; i < BN / 32; ++i) {
      const u16* srcB = W2 + (size_t)(o0 + i * 32 + lrow) * K2 + k0 + lce;
      __builtin_amdgcn_global_load_lds(
          (const __attribute__((address_space(1))) void*)srcB,
          (__attribute__((address_space(3))) void*)&Bs[(i * 256 + (wid << 6)) * 8],
          16, 0, 0);
    }
    __syncthreads();
#pragma unroll
    for (int kk = 0; kk < 2; ++kk) {
      h8 a[FM], b[FN];
      const int ch0 = (kk << 2) + (lane >> 4);
      const int chs = ch0 ^ (lane & 7);
#pragma unroll
      for (int m = 0; m < FM; ++m) {
        const int R = wr * (FM * 16) + m * 16 + (lane & 15);
        a[m] = *(const h8*)&As[R * 64 + chs * 8];
      }
#pragma unroll
      for (int n = 0; n < FN; ++n) {
        const int Rb = wc * (FN * 16) + n * 16 + (lane & 15);
        b[n] = *(const h8*)&Bs[Rb * 64 + chs * 8];
      }
#pragma unroll
      for (int m = 0; m < FM; ++m)
#pragma unroll
        for (int n = 0; n < FN; ++n)
          acc[m][n] = __builtin_amdgcn_mfma_f32_16x16x32_f16(a[m], b[n], acc[m][n], 0, 0, 0);
    }
    __syncthreads();
    kA += 64;
    if (kA >= AW) kA = 0;
  }
  const int crow = (lane >> 4) << 2, ccol = lane & 15;
#pragma unroll
  for (int m = 0; m < FM; ++m)
#pragma unroll
    for (int n = 0; n < FN; ++n)
#pragma unroll
      for (int j = 0; j < 4; ++j) {
        const size_t idx =
            (size_t)(r0 + wr * (FM * 16) + (m << 4) + crow + j) * O +
            o0 + wc * (FN * 16) + (n << 4) + ccol;
        float v = acc[m][n][j];
        if (resid) v += resid[idx];
        Y[idx] = v;
      }
  if (STATS) {
    // per-column partials over this block's BM rows (resid==nullptr path).
    float s1[FN], s2[FN];
#pragma unroll
    for (int n = 0; n < FN; ++n) {
      s1[n] = 0.f; s2[n] = 0.f;
#pragma unroll
      for (int m = 0; m < FM; ++m)
#pragma unroll
        for (int j = 0; j < 4; ++j) {
          const float v = acc[m][n][j];
          s1[n] += v; s2[n] += v * v;
        }
    }
#pragma unroll
    for (int n = 0; n < FN; ++n) {  // reduce over the 4 row-groups of the wave
      s1[n] += __shfl_xor(s1[n], 16); s1[n] += __shfl_xor(s1[n], 32);
      s2[n] += __shfl_xor(s2[n], 16); s2[n] += __shfl_xor(s2[n], 32);
    }
    float* sb = (float*)As;  // reuse LDS: 2*WM*BN floats
    if (lane < 16) {
#pragma unroll
      for (int n = 0; n < FN; ++n) {
        const int cl = wc * (FN * 16) + n * 16 + lane;
        sb[wr * BN + cl] = s1[n];
        sb[WM * BN + wr * BN + cl] = s2[n];
      }
    }
    __syncthreads();
    if (tid < BN) {
      float a = 0.f, b = 0.f;
#pragma unroll
      for (int w = 0; w < WM; ++w) {
        a += sb[w * BN + tid];
        b += sb[WM * BN + w * BN + tid];
      }
      p1[(size_t)by * O + o0 + tid] = a;
      p2[(size_t)by * O + o0 + tid] = b;
    }
  }
}

// ---------------------------------------------------------------------------
// BN stats pass 2: reduce npanels partials -> mean + rsqrt(var+eps).
__global__ __launch_bounds__(256) void bn_stats2(const float* __restrict__ p1,
    const float* __restrict__ p2, float* __restrict__ mu,
    float* __restrict__ rinv, int O, int npanels) {
  const int o = blockIdx.x * 256 + threadIdx.x;
  float s1 = 0.f, s2 = 0.f;
  for (int j = 0; j < npanels; ++j) {
    s1 += p1[(size_t)j * O + o];
    s2 += p2[(size_t)j * O + o];
  }
  const float m = s1 * (1.0f / 16384.f);
  const float v = s2 * (1.0f / 16384.f) - m * m;
  mu[o] = m;
  rinv[o] = 1.0f / sqrtf(v + 1e-5f);
}

// Fused QKV BN + spike: Yq is R x 768 = [q|k|v] channels; writes 3 spike bufs.
__global__ __launch_bounds__(256) void qkv_spike(const float* __restrict__ Yq,
    const float* __restrict__ mu, const float* __restrict__ rinv,
    const float* __restrict__ qg, const float* __restrict__ qb,
    const float* __restrict__ kg, const float* __restrict__ kb,
    const float* __restrict__ vg, const float* __restrict__ vb,
    u16* __restrict__ qs, u16* __restrict__ ks, u16* __restrict__ vs) {
  const int i = blockIdx.x * 256 + threadIdx.x;  // float4 id over R*192
  const int r = i / 192, c4 = i - r * 192;
  const int c = c4 << 2;
  const int sel = c >> 8, cc = c & 255;
  const float4 y = ((const float4*)Yq)[i];
  const float4 m4 = *(const float4*)(mu + c);
  const float4 r4 = *(const float4*)(rinv + c);
  const float* g = (sel == 0) ? qg : (sel == 1) ? kg : vg;
  const float* b = (sel == 0) ? qb : (sel == 1) ? kb : vb;
  const float4 g4 = *(const float4*)(g + cc);
  const float4 b4 = *(const float4*)(b + cc);
  ushort4 s;
  s.x = ((y.x - m4.x) * r4.x * g4.x + b4.x >= 1.0f) ? (u16)0x3C00 : (u16)0;
  s.y = ((y.y - m4.y) * r4.y * g4.y + b4.y >= 1.0f) ? (u16)0x3C00 : (u16)0;
  s.z = ((y.z - m4.z) * r4.z * g4.z + b4.z >= 1.0f) ? (u16)0x3C00 : (u16)0;
  s.w = ((y.w - m4.w) * r4.w * g4.w + b4.w >= 1.0f) ? (u16)0x3C00 : (u16)0;
  u16* dst = ((sel == 0) ? qs : (sel == 1) ? ks : vs) + (size_t)r * 256 + cc;
  *(ushort4*)dst = s;
}

// BN affine + Heaviside spike -> f16 spikes {0, 0x3C00}.
__global__ __launch_bounds__(256) void bn_spike_f16(const float* __restrict__ Y,
    const float* __restrict__ mu, const float* __restrict__ rinv,
    const float* __restrict__ g, const float* __restrict__ b,
    u16* __restrict__ S, int O) {
  const int i = blockIdx.x * 256 + threadIdx.x;
  const int c = (i << 2) & (O - 1);
  const float4 y = ((const float4*)Y)[i];
  const float4 m4 = *(const float4*)(mu + c);
  const float4 r4 = *(const float4*)(rinv + c);
  const float4 g4 = *(const float4*)(g + c);
  const float4 b4 = *(const float4*)(b + c);
  ushort4 s;
  s.x = ((y.x - m4.x) * r4.x * g4.x + b4.x >= 1.0f) ? (u16)0x3C00 : (u16)0;
  s.y = ((y.y - m4.y) * r4.y * g4.y + b4.y >= 1.0f) ? (u16)0x3C00 : (u16)0;
  s.z = ((y.z - m4.z) * r4.z * g4.z + b4.z >= 1.0f) ? (u16)0x3C00 : (u16)0;
  s.w = ((y.w - m4.w) * r4.w * g4.w + b4.w >= 1.0f) ? (u16)0x3C00 : (u16)0;
  ((ushort4*)S)[i] = s;
}

// BN affine + spike added into fp32 output (final residual).
__global__ __launch_bounds__(256) void bn_spike_add(const float* __restrict__ Y,
    const float* __restrict__ mu, const float* __restrict__ rinv,
    const float* __restrict__ g, const float* __restrict__ b,
    float* __restrict__ addOut, int O) {
  const int i = blockIdx.x * 256 + threadIdx.x;
  const int c = (i << 2) & (O - 1);
  const float4 y = ((const float4*)Y)[i];
  const float4 m4 = *(const float4*)(mu + c);
  const float4 r4 = *(const float4*)(rinv + c);
  const float4 g4 = *(const float4*)(g + c);
  const float4 b4 = *(const float4*)(b + c);
  float4 o4 = ((const float4*)addOut)[i];
  o4.x += ((y.x - m4.x) * r4.x * g4.x + b4.x >= 1.0f) ? 1.0f : 0.0f;
  o4.y += ((y.y - m4.y) * r4.y * g4.y + b4.y >= 1.0f) ? 1.0f : 0.0f;
  o4.z += ((y.z - m4.z) * r4.z * g4.z + b4.z >= 1.0f) ? 1.0f : 0.0f;
  o4.w += ((y.w - m4.w) * r4.w * g4.w + b4.w >= 1.0f) ? 1.0f : 0.0f;
  ((float4*)addOut)[i] = o4;
}

// ---------------------------------------------------------------------------
// M[b,h] = K^T V (64x64), split over n into 16 partials. Inputs: f16 spikes.
__global__ __launch_bounds__(256) void attn_kv(const u16* __restrict__ Ksp,
    const u16* __restrict__ Vsp, float* __restrict__ Mpart) {
  const int bh = blockIdx.x, sp = blockIdx.y;
  const int b = bh >> 2, h = bh & 3;
  const int t = threadIdx.x;
  const int gq = t >> 6, e = t & 63;
  const size_t base = (size_t)b * NN * CC + (h << 6);
  __shared__ float ks[16][64], vs[16][64];
  float acc[16] = {};
  const int lrow = t >> 4, lf = (t & 15) << 2;
  for (int n0 = sp * 128; n0 < sp * 128 + 128; n0 += 16) {
    const ushort4 kq = *(const ushort4*)(Ksp + base + (size_t)(n0 + lrow) * CC + lf);
    const ushort4 vq = *(const ushort4*)(Vsp + base + (size_t)(n0 + lrow) * CC + lf);
    __syncthreads();
    ks[lrow][lf + 0] = h2f(kq.x); ks[lrow][lf + 1] = h2f(kq.y);
    ks[lrow][lf + 2] = h2f(kq.z); ks[lrow][lf + 3] = h2f(kq.w);
    vs[lrow][lf + 0] = h2f(vq.x); vs[lrow][lf + 1] = h2f(vq.y);
    vs[lrow][lf + 2] = h2f(vq.z); vs[lrow][lf + 3] = h2f(vq.w);
    __syncthreads();
#pragma unroll
    for (int nn = 0; nn < 16; ++nn) {
      const float vv = vs[nn][e];
#pragma unroll
      for (int i = 0; i < 16; ++i) acc[i] += ks[nn][(gq << 4) + i] * vv;
    }
  }
  float* mp = Mpart + ((size_t)bh * 16 + sp) * 4096;
#pragma unroll
  for (int i = 0; i < 16; ++i) mp[((gq << 4) + i) * 64 + e] = acc[i];
}

__global__ __launch_bounds__(256) void attn_kv_reduce(
    const float* __restrict__ Mpart, float* __restrict__ M) {
  const int i = blockIdx.x * 256 + threadIdx.x;
  const int bh = i >> 12, j = i & 4095;
  float s = 0.f;
#pragma unroll
  for (int sp = 0; sp < 16; ++sp)
    s += Mpart[((size_t)bh * 16 + sp) * 4096 + j];
  M[i] = s;
}

// o = 0.125 * q @ M (exact), written as EXACT 2-term f16 [o1|o2] (width 512).
__global__ __launch_bounds__(256) void attn_qm(const u16* __restrict__ Qsp,
    const float* __restrict__ M, u16* __restrict__ O2) {
  const int h = blockIdx.x;
  const int r0 = blockIdx.y << 6;
  const int b = blockIdx.y >> 5;
  const int t = threadIdx.x;
  const int e = t & 63, rg = t >> 6;
  __shared__ float Ms[64][64];
  __shared__ float qs[64][64];
  const float* Mb = M + ((size_t)(b * 4 + h) << 12);
  for (int i = t; i < 4096; i += 256) ((float*)Ms)[i] = Mb[i];
  for (int rl = rg; rl < 64; rl += 4)
    qs[rl][e] = h2f(Qsp[(size_t)(r0 + rl) * CC + (h << 6) + e]);
  __syncthreads();
  for (int rl = rg; rl < 64; rl += 4) {
    float acc = 0.f;
#pragma unroll
    for (int d = 0; d < 64; ++d) acc += qs[rl][d] * Ms[d][e];
    const float o = 0.125f * acc;   // exact multiple of 1/8
    const u16 hi = f2h(o);
    const u16 lo = f2h(o - h2f(hi));  // exact 2-term
    O2[(size_t)(r0 + rl) * 512 + (h << 6) + e] = hi;
    O2[(size_t)(r0 + rl) * 512 + 256 + (h << 6) + e] = lo;
  }
}

// ---------------------------------------------------------------------------
extern "C" void kernel_launch(void* const* d_in, const int* in_sizes, int n_in,
                              void* d_out, int out_size, void* d_ws,
                              size_t ws_size, hipStream_t stream) {
  const float* x    = (const float*)d_in[0];
  const float* ln1g = (const float*)d_in[1];
  const float* ln1b = (const float*)d_in[2];
  const float* wq   = (const float*)d_in[3];
  const float* qg   = (const float*)d_in[4];
  const float* qb   = (const float*)d_in[5];
  const float* wk   = (const float*)d_in[6];
  const float* kg   = (const float*)d_in[7];
  const float* kb   = (const float*)d_in[8];
  const float* wv   = (const float*)d_in[9];
  const float* vg   = (const float*)d_in[10];
  const float* vb   = (const float*)d_in[11];
  const float* wo   = (const float*)d_in[12];
  const float* ln2g = (const float*)d_in[13];
  const float* ln2b = (const float*)d_in[14];
  const float* w1   = (const float*)d_in[15];
  const float* b1g  = (const float*)d_in[16];
  const float* b1b  = (const float*)d_in[17];
  const float* w2   = (const float*)d_in[18];
  const float* b2g  = (const float*)d_in[19];
  const float* b2b  = (const float*)d_in[20];
  float* out = (float*)d_out;
  char* ws = (char*)d_ws;
  const size_t MB = 1u << 20;
  // Arena (<=137.1 MB), phase-overlaid:
  u16*   h1s   = (u16*)(ws);               // [0,16)   dead after QKV gemm
  float* Yq    = (float*)(ws + 16 * MB);   // [16,64)  R x 768 fp32
  u16*   qs_   = (u16*)(ws + 64 * MB);     // [64,72)
  u16*   ks_   = (u16*)(ws + 72 * MB);     // [72,80)
  u16*   vs_   = (u16*)(ws + 80 * MB);     // [80,88)
  float* Mpart = (float*)(ws + 88 * MB);   // [88,96)  8 MB
  float* Mful  = (float*)(ws + 96 * MB);   // [96,96.5)
  u16*   o2    = (u16*)(ws);               // [0,16)   overlays h1s (dead)
  u16*   h2s   = (u16*)(ws + 16 * MB);     // [16,32)  overlays Yq-lo (dead)
  float* Ym    = (float*)(ws + 32 * MB);   // [32,96)  R x 1024 fp32 (MLP)
  u16*   m1    = (u16*)(ws + 97 * MB);     // [97,129) R x 1024 f16
  u16*   Wqkv  = (u16*)(ws + 129 * MB);    // 768 x 1024 f16 = 1.5 MB
  u16*   wo2   = (u16*)(ws + 131 * MB);    // 256 x 1024 f16 = 0.5 MB
  u16*   w12   = (u16*)(ws + 132 * MB);    // 1024 x 1024 f16 = 2 MB
  u16*   w22   = (u16*)(ws + 134 * MB);    // 256 x 2048 f16 = 1 MB
  float* p1    = (float*)(ws + 135 * MB);  // 1 MB (npanels x O)
  float* p2    = (float*)(ws + 136 * MB);  // 1 MB
  float* mu    = (float*)(ws + 137 * MB);
  float* rinv  = (float*)(ws + 137 * MB + 32768);

  const dim3 blk(256);

  // Weight splits (f16 2-term), one dispatch
  split_all<<<3072, blk, 0, stream>>>(wq, wk, wv, wo, w1, w2, Wqkv, wo2, w12, w22);

  // 1. h1 = LN1(x) -> split f16
  ln_split<<<RR / 4, blk, 0, stream>>>(x, ln1g, ln1b, h1s);

  // 2. Fused QKV projection (MFMA, O=768) + fused BN pass-1
  gemm_sp<128, 128, 2, 2, 1><<<dim3(6, 128), blk, 0, stream>>>(
      h1s, 512, Wqkv, 1024, nullptr, Yq, 768, p1, p2);

  // 3. BN stats finalize + spike for q|k|v
  bn_stats2<<<3, blk, 0, stream>>>(p1, p2, mu, rinv, 768, 128);
  qkv_spike<<<RR * 192 / 256, blk, 0, stream>>>(Yq, mu, rinv, qg, qb, kg, kb,
                                                vg, vb, qs_, ks_, vs_);

  // 4-6. attention: M = K^T V (exact int), o = 0.125 q@M -> exact 2-term f16
  attn_kv<<<dim3(32, 16), blk, 0, stream>>>(ks_, vs_, Mpart);
  attn_kv_reduce<<<512, blk, 0, stream>>>(Mpart, Mful);
  attn_qm<<<dim3(4, RR / 64), blk, 0, stream>>>(qs_, Mful, o2);

  // 7. x2 = x + o @ wo^T -> out   (MFMA, exact-A x 2-term W, K'=1024)
  gemm_sp<64, 128, 2, 2, 0><<<dim3(2, 256), blk, 0, stream>>>(
      o2, 512, wo2, 1024, x, out, 256, nullptr, nullptr);

  // 8. h2 = LN2(x2) -> split f16
  ln_split<<<RR / 4, blk, 0, stream>>>(out, ln2g, ln2b, h2s);

  // 9-10. MLP1 (2x2 f16 split, K'=1024) + fused BN pass-1 + spike -> m1
  gemm_sp<128, 128, 2, 2, 1><<<dim3(8, 128), blk, 0, stream>>>(
      h2s, 512, w12, 1024, nullptr, Ym, 1024, p1, p2);
  bn_stats2<<<4, blk, 0, stream>>>(p1, p2, mu, rinv, 1024, 128);
  bn_spike_f16<<<16384, blk, 0, stream>>>(Ym, mu, rinv, b1g, b1b, m1, 1024);

  // 11-12. MLP2 (binary-exact A x 2-term W, K'=2048) + BN + spike-add
  gemm_sp<64, 128, 2, 2, 1><<<dim3(2, 256), blk, 0, stream>>>(
      m1, 1024, w22, 2048, nullptr, Ym, 256, p1, p2);
  bn_stats2<<<1, blk, 0, stream>>>(p1, p2, mu, rinv, 256, 256);
  bn_spike_add<<<4096, blk, 0, stream>>>(Ym, mu, rinv, b2g, b2b, out, 256);
}

// Round 6
// 270.677 us; speedup vs baseline: 1.5233x; 1.5233x over previous
//
#include <hip/hip_runtime.h>
#include <cstddef>
#include <cstdint>

#define RR 16384   // B*N rows
#define CC 256
#define NN 2048

typedef __attribute__((ext_vector_type(8))) _Float16 h8;
typedef __attribute__((ext_vector_type(4))) float float4v;
typedef unsigned short u16;

__device__ inline float h2f(u16 u) {
  return (float)__builtin_bit_cast(_Float16, u);
}
__device__ inline u16 f2h(float f) {
  return __builtin_bit_cast(u16, (_Float16)f);
}

// ---------------------------------------------------------------------------
// LayerNorm -> split f16 [hi(256) | lo(256)] per row.
__global__ __launch_bounds__(256) void ln_split(const float* __restrict__ x,
    const float* __restrict__ g, const float* __restrict__ b,
    u16* __restrict__ out) {
  const int wave = threadIdx.x >> 6, lane = threadIdx.x & 63;
  const int row = (blockIdx.x << 2) + wave;
  const float4 v = ((const float4*)(x + (size_t)row * CC))[lane];
  float s1 = v.x + v.y + v.z + v.w;
  float s2 = v.x * v.x + v.y * v.y + v.z * v.z + v.w * v.w;
#pragma unroll
  for (int o = 32; o > 0; o >>= 1) {
    s1 += __shfl_xor(s1, o);
    s2 += __shfl_xor(s2, o);
  }
  const float mu = s1 * (1.0f / CC);
  const float var = s2 * (1.0f / CC) - mu * mu;
  const float rs = 1.0f / sqrtf(var + 1e-5f);
  const float4 gg = ((const float4*)g)[lane];
  const float4 bb = ((const float4*)b)[lane];
  float o4[4];
  o4[0] = (v.x - mu) * rs * gg.x + bb.x;
  o4[1] = (v.y - mu) * rs * gg.y + bb.y;
  o4[2] = (v.z - mu) * rs * gg.z + bb.z;
  o4[3] = (v.w - mu) * rs * gg.w + bb.w;
  ushort4 hi, lo;
  hi.x = f2h(o4[0]); lo.x = f2h(o4[0] - h2f(hi.x));
  hi.y = f2h(o4[1]); lo.y = f2h(o4[1] - h2f(hi.y));
  hi.z = f2h(o4[2]); lo.z = f2h(o4[2] - h2f(hi.z));
  hi.w = f2h(o4[3]); lo.w = f2h(o4[3] - h2f(hi.w));
  *(ushort4*)(out + (size_t)row * 512 + (lane << 2)) = hi;
  *(ushort4*)(out + (size_t)row * 512 + 256 + (lane << 2)) = lo;
}

// ---------------------------------------------------------------------------
// All weight splits in ONE dispatch (3072 blocks).
__global__ __launch_bounds__(256) void split_all(const float* __restrict__ wq,
    const float* __restrict__ wk, const float* __restrict__ wv,
    const float* __restrict__ wo, const float* __restrict__ w1,
    const float* __restrict__ w2, u16* __restrict__ Wqkv,
    u16* __restrict__ wo2, u16* __restrict__ w12, u16* __restrict__ w22) {
  const int bid = blockIdx.x;
  if (bid < 1024) {  // 4-term splits, K=256
    const float* W; u16* D; int rowoff; int li;
    if (bid < 768) {
      W = (bid < 256) ? wq : (bid < 512) ? wk : wv;
      D = Wqkv; rowoff = (bid >> 8) << 8;
      li = (bid & 255) * 256 + threadIdx.x;
    } else {
      W = wo; D = wo2; rowoff = 0;
      li = (bid - 768) * 256 + threadIdx.x;
    }
    const int o = li >> 8, k = li & 255;
    const float w = W[li];
    const u16 h1 = f2h(w);
    const u16 h2 = f2h(w - h2f(h1));
    u16* base = D + (size_t)(o + rowoff) * 1024;
    base[k] = h1; base[256 + k] = h1; base[512 + k] = h2; base[768 + k] = h2;
  } else if (bid < 2048) {  // w1 4-term
    const int li = (bid - 1024) * 256 + threadIdx.x;
    const int o = li >> 8, k = li & 255;
    const float w = w1[li];
    const u16 h1 = f2h(w);
    const u16 h2 = f2h(w - h2f(h1));
    u16* base = w12 + (size_t)o * 1024;
    base[k] = h1; base[256 + k] = h1; base[512 + k] = h2; base[768 + k] = h2;
  } else {  // w2 2-term, K=1024
    const int li = (bid - 2048) * 256 + threadIdx.x;
    const int o = li >> 10, k = li & 1023;
    const float w = w2[li];
    const u16 h1 = f2h(w);
    const u16 h2 = f2h(w - h2f(h1));
    u16* base = w22 + (size_t)o * 2048;
    base[k] = h1; base[1024 + k] = h2;
  }
}

// ---------------------------------------------------------------------------
// MFMA f16 GEMM: Y[r,o] = sum_{k'} A[r, k' mod AW] * W2[o, k']  (+resid)
// Tile BM x BN, BK=64, 4 waves (WMxWN), mfma_f32_16x16x32_f16.
// T2 LDS swizzle both-sides; T1 XCD-aware block swizzle (nwg % 8 == 0).
// STATS: fused BN pass-1 per row-panel into p1/p2[by*O + col].
template <int BM, int BN, int WM, int WN, int STATS>
__global__ __launch_bounds__(256) void gemm_sp(
    const u16* __restrict__ A, int AW,
    const u16* __restrict__ W2, int K2,
    const float* __restrict__ resid, float* __restrict__ Y, int O,
    float* __restrict__ p1, float* __restrict__ p2) {
  constexpr int FM = BM / (WM * 16);
  constexpr int FN = BN / (WN * 16);
  __shared__ __align__(16) u16 As[BM * 64];
  __shared__ __align__(16) u16 Bs[BN * 64];
  const int tid = threadIdx.x;
  const int lane = tid & 63, wid = tid >> 6;
  const int wr = wid / WN, wc = wid % WN;
  const int gx = gridDim.x;
  const int lid = blockIdx.y * gx + blockIdx.x;
  const int chunk = (gx * gridDim.y) >> 3;
  const int nid = (lid & 7) * chunk + (lid >> 3);
  const int bx = nid % gx, by = nid / gx;
  const int r0 = by * BM, o0 = bx * BN;
  const int lrow = tid >> 3;                             // 0..31
  const int lce = ((tid & 7) ^ ((tid >> 3) & 7)) << 3;   // swizzled src chunk
  float4v acc[FM][FN] = {};
  int kA = 0;
  for (int k0 = 0; k0 < K2; k0 += 64) {
#pragma unroll
    for (int i = 0; i < BM / 32; ++i) {
      const u16* srcA = A + (size_t)(r0 + i * 32 + lrow) * AW + kA + lce;
      __builtin_amdgcn_global_load_lds(
          (const __attribute__((address_space(1))) void*)srcA,
          (__attribute__((address_space(3))) void*)&As[(i * 256 + (wid << 6)) * 8],
          16, 0, 0);
    }
#pragma unroll
    for (int i = 0; i < BN / 32; ++i) {
      const u16* srcB = W2 + (size_t)(o0 + i * 32 + lrow) * K2 + k0 + lce;
      __builtin_amdgcn_global_load_lds(
          (const __attribute__((address_space(1))) void*)srcB,
          (__attribute__((address_space(3))) void*)&Bs[(i * 256 + (wid << 6)) * 8],
          16, 0, 0);
    }
    __syncthreads();
#pragma unroll
    for (int kk = 0; kk < 2; ++kk) {
      h8 a[FM], b[FN];
      const int ch0 = (kk << 2) + (lane >> 4);
      const int chs = ch0 ^ (lane & 7);
#pragma unroll
      for (int m = 0; m < FM; ++m) {
        const int R = wr * (FM * 16) + m * 16 + (lane & 15);
        a[m] = *(const h8*)&As[R * 64 + chs * 8];
      }
#pragma unroll
      for (int n = 0; n < FN; ++n) {
        const int Rb = wc * (FN * 16) + n * 16 + (lane & 15);
        b[n] = *(const h8*)&Bs[Rb * 64 + chs * 8];
      }
#pragma unroll
      for (int m = 0; m < FM; ++m)
#pragma unroll
        for (int n = 0; n < FN; ++n)
          acc[m][n] = __builtin_amdgcn_mfma_f32_16x16x32_f16(a[m], b[n], acc[m][n], 0, 0, 0);
    }
    __syncthreads();
    kA += 64;
    if (kA >= AW) kA = 0;
  }
  const int crow = (lane >> 4) << 2, ccol = lane & 15;
#pragma unroll
  for (int m = 0; m < FM; ++m)
#pragma unroll
    for (int n = 0; n < FN; ++n)
#pragma unroll
      for (int j = 0; j < 4; ++j) {
        const size_t idx =
            (size_t)(r0 + wr * (FM * 16) + (m << 4) + crow + j) * O +
            o0 + wc * (FN * 16) + (n << 4) + ccol;
        float v = acc[m][n][j];
        if (resid) v += resid[idx];
        Y[idx] = v;
      }
  if (STATS) {
    float s1[FN], s2[FN];
#pragma unroll
    for (int n = 0; n < FN; ++n) {
      s1[n] = 0.f; s2[n] = 0.f;
#pragma unroll
      for (int m = 0; m < FM; ++m)
#pragma unroll
        for (int j = 0; j < 4; ++j) {
          const float v = acc[m][n][j];
          s1[n] += v; s2[n] += v * v;
        }
    }
#pragma unroll
    for (int n = 0; n < FN; ++n) {
      s1[n] += __shfl_xor(s1[n], 16); s1[n] += __shfl_xor(s1[n], 32);
      s2[n] += __shfl_xor(s2[n], 16); s2[n] += __shfl_xor(s2[n], 32);
    }
    float* sb = (float*)As;
    if (lane < 16) {
#pragma unroll
      for (int n = 0; n < FN; ++n) {
        const int cl = wc * (FN * 16) + n * 16 + lane;
        sb[wr * BN + cl] = s1[n];
        sb[WM * BN + wr * BN + cl] = s2[n];
      }
    }
    __syncthreads();
    if (tid < BN) {
      float a = 0.f, b = 0.f;
#pragma unroll
      for (int w = 0; w < WM; ++w) {
        a += sb[w * BN + tid];
        b += sb[WM * BN + w * BN + tid];
      }
      p1[(size_t)by * O + o0 + tid] = a;
      p2[(size_t)by * O + o0 + tid] = b;
    }
  }
}

// ---------------------------------------------------------------------------
// BN stats pass 2 (PARALLEL): one block per 64 channels; 4 waves split the
// panel dim; coalesced lane-per-channel reads; LDS reduce (fixed order).
__global__ __launch_bounds__(256) void bn_stats2(const float* __restrict__ p1,
    const float* __restrict__ p2, float* __restrict__ mu,
    float* __restrict__ rinv, int O, int npanels) {
  const int c0 = blockIdx.x << 6;
  const int c = threadIdx.x & 63;
  const int jg = threadIdx.x >> 6;   // 0..3
  float s1 = 0.f, s2 = 0.f;
#pragma unroll 4
  for (int j = jg; j < npanels; j += 4) {
    s1 += p1[(size_t)j * O + c0 + c];
    s2 += p2[(size_t)j * O + c0 + c];
  }
  __shared__ float sb[8][64];
  sb[jg][c] = s1;
  sb[4 + jg][c] = s2;
  __syncthreads();
  if (threadIdx.x < 64) {
    const float a = ((sb[0][c] + sb[1][c]) + (sb[2][c] + sb[3][c]));
    const float b = ((sb[4][c] + sb[5][c]) + (sb[6][c] + sb[7][c]));
    const float m = a * (1.0f / 16384.f);
    const float v = b * (1.0f / 16384.f) - m * m;
    mu[c0 + c] = m;
    rinv[c0 + c] = 1.0f / sqrtf(v + 1e-5f);
  }
}

// Fused QKV BN + spike: Yq is R x 768 = [q|k|v] channels; writes 3 spike bufs.
__global__ __launch_bounds__(256) void qkv_spike(const float* __restrict__ Yq,
    const float* __restrict__ mu, const float* __restrict__ rinv,
    const float* __restrict__ qg, const float* __restrict__ qb,
    const float* __restrict__ kg, const float* __restrict__ kb,
    const float* __restrict__ vg, const float* __restrict__ vb,
    u16* __restrict__ qs, u16* __restrict__ ks, u16* __restrict__ vs) {
  const int i = blockIdx.x * 256 + threadIdx.x;  // float4 id over R*192
  const int r = i / 192, c4 = i - r * 192;
  const int c = c4 << 2;
  const int sel = c >> 8, cc = c & 255;
  const float4 y = ((const float4*)Yq)[i];
  const float4 m4 = *(const float4*)(mu + c);
  const float4 r4 = *(const float4*)(rinv + c);
  const float* g = (sel == 0) ? qg : (sel == 1) ? kg : vg;
  const float* b = (sel == 0) ? qb : (sel == 1) ? kb : vb;
  const float4 g4 = *(const float4*)(g + cc);
  const float4 b4 = *(const float4*)(b + cc);
  ushort4 s;
  s.x = ((y.x - m4.x) * r4.x * g4.x + b4.x >= 1.0f) ? (u16)0x3C00 : (u16)0;
  s.y = ((y.y - m4.y) * r4.y * g4.y + b4.y >= 1.0f) ? (u16)0x3C00 : (u16)0;
  s.z = ((y.z - m4.z) * r4.z * g4.z + b4.z >= 1.0f) ? (u16)0x3C00 : (u16)0;
  s.w = ((y.w - m4.w) * r4.w * g4.w + b4.w >= 1.0f) ? (u16)0x3C00 : (u16)0;
  u16* dst = ((sel == 0) ? qs : (sel == 1) ? ks : vs) + (size_t)r * 256 + cc;
  *(ushort4*)dst = s;
}

// BN affine + Heaviside spike -> f16 spikes {0, 0x3C00}.
__global__ __launch_bounds__(256) void bn_spike_f16(const float* __restrict__ Y,
    const float* __restrict__ mu, const float* __restrict__ rinv,
    const float* __restrict__ g, const float* __restrict__ b,
    u16* __restrict__ S, int O) {
  const int i = blockIdx.x * 256 + threadIdx.x;
  const int c = (i << 2) & (O - 1);
  const float4 y = ((const float4*)Y)[i];
  const float4 m4 = *(const float4*)(mu + c);
  const float4 r4 = *(const float4*)(rinv + c);
  const float4 g4 = *(const float4*)(g + c);
  const float4 b4 = *(const float4*)(b + c);
  ushort4 s;
  s.x = ((y.x - m4.x) * r4.x * g4.x + b4.x >= 1.0f) ? (u16)0x3C00 : (u16)0;
  s.y = ((y.y - m4.y) * r4.y * g4.y + b4.y >= 1.0f) ? (u16)0x3C00 : (u16)0;
  s.z = ((y.z - m4.z) * r4.z * g4.z + b4.z >= 1.0f) ? (u16)0x3C00 : (u16)0;
  s.w = ((y.w - m4.w) * r4.w * g4.w + b4.w >= 1.0f) ? (u16)0x3C00 : (u16)0;
  ((ushort4*)S)[i] = s;
}

// BN affine + spike added into fp32 output (final residual).
__global__ __launch_bounds__(256) void bn_spike_add(const float* __restrict__ Y,
    const float* __restrict__ mu, const float* __restrict__ rinv,
    const float* __restrict__ g, const float* __restrict__ b,
    float* __restrict__ addOut, int O) {
  const int i = blockIdx.x * 256 + threadIdx.x;
  const int c = (i << 2) & (O - 1);
  const float4 y = ((const float4*)Y)[i];
  const float4 m4 = *(const float4*)(mu + c);
  const float4 r4 = *(const float4*)(rinv + c);
  const float4 g4 = *(const float4*)(g + c);
  const float4 b4 = *(const float4*)(b + c);
  float4 o4 = ((const float4*)addOut)[i];
  o4.x += ((y.x - m4.x) * r4.x * g4.x + b4.x >= 1.0f) ? 1.0f : 0.0f;
  o4.y += ((y.y - m4.y) * r4.y * g4.y + b4.y >= 1.0f) ? 1.0f : 0.0f;
  o4.z += ((y.z - m4.z) * r4.z * g4.z + b4.z >= 1.0f) ? 1.0f : 0.0f;
  o4.w += ((y.w - m4.w) * r4.w * g4.w + b4.w >= 1.0f) ? 1.0f : 0.0f;
  ((float4*)addOut)[i] = o4;
}

// ---------------------------------------------------------------------------
// M[b,h] = K^T V (64x64), split over n into 16 partials. Inputs: f16 spikes.
__global__ __launch_bounds__(256) void attn_kv(const u16* __restrict__ Ksp,
    const u16* __restrict__ Vsp, float* __restrict__ Mpart) {
  const int bh = blockIdx.x, sp = blockIdx.y;
  const int b = bh >> 2, h = bh & 3;
  const int t = threadIdx.x;
  const int gq = t >> 6, e = t & 63;
  const size_t base = (size_t)b * NN * CC + (h << 6);
  __shared__ float ks[16][64], vs[16][64];
  float acc[16] = {};
  const int lrow = t >> 4, lf = (t & 15) << 2;
  for (int n0 = sp * 128; n0 < sp * 128 + 128; n0 += 16) {
    const ushort4 kq = *(const ushort4*)(Ksp + base + (size_t)(n0 + lrow) * CC + lf);
    const ushort4 vq = *(const ushort4*)(Vsp + base + (size_t)(n0 + lrow) * CC + lf);
    __syncthreads();
    ks[lrow][lf + 0] = h2f(kq.x); ks[lrow][lf + 1] = h2f(kq.y);
    ks[lrow][lf + 2] = h2f(kq.z); ks[lrow][lf + 3] = h2f(kq.w);
    vs[lrow][lf + 0] = h2f(vq.x); vs[lrow][lf + 1] = h2f(vq.y);
    vs[lrow][lf + 2] = h2f(vq.z); vs[lrow][lf + 3] = h2f(vq.w);
    __syncthreads();
#pragma unroll
    for (int nn = 0; nn < 16; ++nn) {
      const float vv = vs[nn][e];
#pragma unroll
      for (int i = 0; i < 16; ++i) acc[i] += ks[nn][(gq << 4) + i] * vv;
    }
  }
  float* mp = Mpart + ((size_t)bh * 16 + sp) * 4096;
#pragma unroll
  for (int i = 0; i < 16; ++i) mp[((gq << 4) + i) * 64 + e] = acc[i];
}

__global__ __launch_bounds__(256) void attn_kv_reduce(
    const float* __restrict__ Mpart, float* __restrict__ M) {
  const int i = blockIdx.x * 256 + threadIdx.x;
  const int bh = i >> 12, j = i & 4095;
  float s = 0.f;
#pragma unroll
  for (int sp = 0; sp < 16; ++sp)
    s += Mpart[((size_t)bh * 16 + sp) * 4096 + j];
  M[i] = s;
}

// o = 0.125 * q @ M (exact), written as EXACT 2-term f16 [o1|o2] (width 512).
__global__ __launch_bounds__(256) void attn_qm(const u16* __restrict__ Qsp,
    const float* __restrict__ M, u16* __restrict__ O2) {
  const int h = blockIdx.x;
  const int r0 = blockIdx.y << 6;
  const int b = blockIdx.y >> 5;
  const int t = threadIdx.x;
  const int e = t & 63, rg = t >> 6;
  __shared__ float Ms[64][64];
  __shared__ float qs[64][64];
  const float* Mb = M + ((size_t)(b * 4 + h) << 12);
  for (int i = t; i < 4096; i += 256) ((float*)Ms)[i] = Mb[i];
  for (int rl = rg; rl < 64; rl += 4)
    qs[rl][e] = h2f(Qsp[(size_t)(r0 + rl) * CC + (h << 6) + e]);
  __syncthreads();
  for (int rl = rg; rl < 64; rl += 4) {
    float acc = 0.f;
#pragma unroll
    for (int d = 0; d < 64; ++d) acc += qs[rl][d] * Ms[d][e];
    const float o = 0.125f * acc;   // exact multiple of 1/8
    const u16 hi = f2h(o);
    const u16 lo = f2h(o - h2f(hi));  // exact 2-term
    O2[(size_t)(r0 + rl) * 512 + (h << 6) + e] = hi;
    O2[(size_t)(r0 + rl) * 512 + 256 + (h << 6) + e] = lo;
  }
}

// ---------------------------------------------------------------------------
extern "C" void kernel_launch(void* const* d_in, const int* in_sizes, int n_in,
                              void* d_out, int out_size, void* d_ws,
                              size_t ws_size, hipStream_t stream) {
  const float* x    = (const float*)d_in[0];
  const float* ln1g = (const float*)d_in[1];
  const float* ln1b = (const float*)d_in[2];
  const float* wq   = (const float*)d_in[3];
  const float* qg   = (const float*)d_in[4];
  const float* qb   = (const float*)d_in[5];
  const float* wk   = (const float*)d_in[6];
  const float* kg   = (const float*)d_in[7];
  const float* kb   = (const float*)d_in[8];
  const float* wv   = (const float*)d_in[9];
  const float* vg   = (const float*)d_in[10];
  const float* vb   = (const float*)d_in[11];
  const float* wo   = (const float*)d_in[12];
  const float* ln2g = (const float*)d_in[13];
  const float* ln2b = (const float*)d_in[14];
  const float* w1   = (const float*)d_in[15];
  const float* b1g  = (const float*)d_in[16];
  const float* b1b  = (const float*)d_in[17];
  const float* w2   = (const float*)d_in[18];
  const float* b2g  = (const float*)d_in[19];
  const float* b2b  = (const float*)d_in[20];
  float* out = (float*)d_out;
  char* ws = (char*)d_ws;
  const size_t MB = 1u << 20;
  u16*   h1s   = (u16*)(ws);               // [0,16)   dead after QKV gemm
  float* Yq    = (float*)(ws + 16 * MB);   // [16,64)  R x 768 fp32
  u16*   qs_   = (u16*)(ws + 64 * MB);     // [64,72)
  u16*   ks_   = (u16*)(ws + 72 * MB);     // [72,80)
  u16*   vs_   = (u16*)(ws + 80 * MB);     // [80,88)
  float* Mpart = (float*)(ws + 88 * MB);   // [88,96)  8 MB
  float* Mful  = (float*)(ws + 96 * MB);   // [96,96.5)
  u16*   o2    = (u16*)(ws);               // [0,16)   overlays h1s (dead)
  u16*   h2s   = (u16*)(ws + 16 * MB);     // [16,32)  overlays Yq-lo (dead)
  float* Ym    = (float*)(ws + 32 * MB);   // [32,96)  R x 1024 fp32 (MLP)
  u16*   m1    = (u16*)(ws + 97 * MB);     // [97,129) R x 1024 f16
  u16*   Wqkv  = (u16*)(ws + 129 * MB);    // 768 x 1024 f16 = 1.5 MB
  u16*   wo2   = (u16*)(ws + 131 * MB);    // 256 x 1024 f16 = 0.5 MB
  u16*   w12   = (u16*)(ws + 132 * MB);    // 1024 x 1024 f16 = 2 MB
  u16*   w22   = (u16*)(ws + 134 * MB);    // 256 x 2048 f16 = 1 MB
  float* p1    = (float*)(ws + 135 * MB);  // 1 MB (npanels x O)
  float* p2    = (float*)(ws + 136 * MB);  // 1 MB
  float* mu    = (float*)(ws + 137 * MB);
  float* rinv  = (float*)(ws + 137 * MB + 32768);

  const dim3 blk(256);

  // Weight splits (f16 2-term), one dispatch
  split_all<<<3072, blk, 0, stream>>>(wq, wk, wv, wo, w1, w2, Wqkv, wo2, w12, w22);

  // 1. h1 = LN1(x) -> split f16
  ln_split<<<RR / 4, blk, 0, stream>>>(x, ln1g, ln1b, h1s);

  // 2. Fused QKV projection (MFMA, O=768) + fused BN pass-1
  gemm_sp<128, 128, 2, 2, 1><<<dim3(6, 128), blk, 0, stream>>>(
      h1s, 512, Wqkv, 1024, nullptr, Yq, 768, p1, p2);

  // 3. BN stats finalize + spike for q|k|v
  bn_stats2<<<12, blk, 0, stream>>>(p1, p2, mu, rinv, 768, 128);
  qkv_spike<<<RR * 192 / 256, blk, 0, stream>>>(Yq, mu, rinv, qg, qb, kg, kb,
                                                vg, vb, qs_, ks_, vs_);

  // 4-6. attention: M = K^T V (exact int), o = 0.125 q@M -> exact 2-term f16
  attn_kv<<<dim3(32, 16), blk, 0, stream>>>(ks_, vs_, Mpart);
  attn_kv_reduce<<<512, blk, 0, stream>>>(Mpart, Mful);
  attn_qm<<<dim3(4, RR / 64), blk, 0, stream>>>(qs_, Mful, o2);

  // 7. x2 = x + o @ wo^T -> out   (MFMA, exact-A x 2-term W, K'=1024)
  gemm_sp<64, 128, 2, 2, 0><<<dim3(2, 256), blk, 0, stream>>>(
      o2, 512, wo2, 1024, x, out, 256, nullptr, nullptr);

  // 8. h2 = LN2(x2) -> split f16
  ln_split<<<RR / 4, blk, 0, stream>>>(out, ln2g, ln2b, h2s);

  // 9-10. MLP1 (2x2 f16 split, K'=1024) + fused BN pass-1 + spike -> m1
  gemm_sp<128, 128, 2, 2, 1><<<dim3(8, 128), blk, 0, stream>>>(
      h2s, 512, w12, 1024, nullptr, Ym, 1024, p1, p2);
  bn_stats2<<<16, blk, 0, stream>>>(p1, p2, mu, rinv, 1024, 128);
  bn_spike_f16<<<16384, blk, 0, stream>>>(Ym, mu, rinv, b1g, b1b, m1, 1024);

  // 11-12. MLP2 (binary-exact A x 2-term W, K'=2048) + BN + spike-add
  gemm_sp<64, 128, 2, 2, 1><<<dim3(2, 256), blk, 0, stream>>>(
      m1, 1024, w22, 2048, nullptr, Ym, 256, p1, p2);
  bn_stats2<<<4, blk, 0, stream>>>(p1, p2, mu, rinv, 256, 256);
  bn_spike_add<<<4096, blk, 0, stream>>>(Ym, mu, rinv, b2g, b2b, out, 256);
}

// Round 7
// 246.662 us; speedup vs baseline: 1.6717x; 1.0974x over previous
//
#include <hip/hip_runtime.h>
#include <cstddef>
#include <cstdint>

#define RR 16384   // B*N rows
#define CC 256
#define NN 2048

typedef __attribute__((ext_vector_type(8))) _Float16 h8;
typedef __attribute__((ext_vector_type(4))) float float4v;
typedef unsigned short u16;

__device__ inline float h2f(u16 u) {
  return (float)__builtin_bit_cast(_Float16, u);
}
__device__ inline u16 f2h(float f) {
  return __builtin_bit_cast(u16, (_Float16)f);
}

// ---------------------------------------------------------------------------
// LayerNorm -> split f16 [hi(256) | lo(256)] per row.
__global__ __launch_bounds__(256) void ln_split(const float* __restrict__ x,
    const float* __restrict__ g, const float* __restrict__ b,
    u16* __restrict__ out) {
  const int wave = threadIdx.x >> 6, lane = threadIdx.x & 63;
  const int row = (blockIdx.x << 2) + wave;
  const float4 v = ((const float4*)(x + (size_t)row * CC))[lane];
  float s1 = v.x + v.y + v.z + v.w;
  float s2 = v.x * v.x + v.y * v.y + v.z * v.z + v.w * v.w;
#pragma unroll
  for (int o = 32; o > 0; o >>= 1) {
    s1 += __shfl_xor(s1, o);
    s2 += __shfl_xor(s2, o);
  }
  const float mu = s1 * (1.0f / CC);
  const float var = s2 * (1.0f / CC) - mu * mu;
  const float rs = 1.0f / sqrtf(var + 1e-5f);
  const float4 gg = ((const float4*)g)[lane];
  const float4 bb = ((const float4*)b)[lane];
  float o4[4];
  o4[0] = (v.x - mu) * rs * gg.x + bb.x;
  o4[1] = (v.y - mu) * rs * gg.y + bb.y;
  o4[2] = (v.z - mu) * rs * gg.z + bb.z;
  o4[3] = (v.w - mu) * rs * gg.w + bb.w;
  ushort4 hi, lo;
  hi.x = f2h(o4[0]); lo.x = f2h(o4[0] - h2f(hi.x));
  hi.y = f2h(o4[1]); lo.y = f2h(o4[1] - h2f(hi.y));
  hi.z = f2h(o4[2]); lo.z = f2h(o4[2] - h2f(hi.z));
  hi.w = f2h(o4[3]); lo.w = f2h(o4[3] - h2f(hi.w));
  *(ushort4*)(out + (size_t)row * 512 + (lane << 2)) = hi;
  *(ushort4*)(out + (size_t)row * 512 + 256 + (lane << 2)) = lo;
}

// ---------------------------------------------------------------------------
// All weight splits in ONE dispatch (3072 blocks).
// 3-term layout [W1|W1|W2] (width 3K) pairs cyclic A=[hi|lo] (AW=2K):
//   products hi*W1 + lo*W1 + hi*W2 (drops lo*W2 ~ 2^-22 rel).
//  [0,768):    wq/wk/wv -> Wqkv (768x768)
//  [768,1024): wo       -> wo2  (256x768)
//  [1024,2048): w1      -> w12  (1024x768)
//  [2048,3072): w2      -> w22  (256x2048, 2-term exact-A)
__global__ __launch_bounds__(256) void split_all(const float* __restrict__ wq,
    const float* __restrict__ wk, const float* __restrict__ wv,
    const float* __restrict__ wo, const float* __restrict__ w1,
    const float* __restrict__ w2, u16* __restrict__ Wqkv,
    u16* __restrict__ wo2, u16* __restrict__ w12, u16* __restrict__ w22) {
  const int bid = blockIdx.x;
  if (bid < 2048) {  // 3-term splits, K=256
    const float* W; u16* D; int rowoff; int li;
    if (bid < 768) {
      W = (bid < 256) ? wq : (bid < 512) ? wk : wv;
      D = Wqkv; rowoff = (bid >> 8) << 8;
      li = (bid & 255) * 256 + threadIdx.x;
    } else if (bid < 1024) {
      W = wo; D = wo2; rowoff = 0;
      li = (bid - 768) * 256 + threadIdx.x;
    } else {
      W = w1; D = w12; rowoff = 0;
      li = (bid - 1024) * 256 + threadIdx.x;
    }
    const int o = li >> 8, k = li & 255;
    const float w = W[li];
    const u16 h1 = f2h(w);
    const u16 h2 = f2h(w - h2f(h1));
    u16* base = D + (size_t)(o + rowoff) * 768;
    base[k] = h1; base[256 + k] = h1; base[512 + k] = h2;
  } else {  // w2 2-term, K=1024
    const int li = (bid - 2048) * 256 + threadIdx.x;
    const int o = li >> 10, k = li & 1023;
    const float w = w2[li];
    const u16 h1 = f2h(w);
    const u16 h2 = f2h(w - h2f(h1));
    u16* base = w22 + (size_t)o * 2048;
    base[k] = h1; base[1024 + k] = h2;
  }
}

// ---------------------------------------------------------------------------
// MFMA f16 GEMM: Y[r,o] = sum_{k'} A[r, k' mod AW] * W2[o, k']  (+resid)
// Tile BM x BN, BK=64, 4 waves (WMxWN), mfma_f32_16x16x32_f16.
// T2 LDS swizzle both-sides; T1 XCD-aware block swizzle (nwg % 8 == 0).
// 2-phase double-buffered pipeline: STAGE(t+1) issued before compute(t);
// leading barrier = vmcnt(NL)+s_barrier (keeps prefetch in flight);
// trailing barrier = lgkmcnt(0)+s_barrier (drains own ds_reads).
// STATS: fused BN pass-1 per row-panel into p1/p2[by*O + col].
template <int BM, int BN, int WM, int WN, int STATS>
__global__ __launch_bounds__(256) void gemm_sp(
    const u16* __restrict__ A, int AW,
    const u16* __restrict__ W2, int K2,
    const float* __restrict__ resid, float* __restrict__ Y, int O,
    float* __restrict__ p1, float* __restrict__ p2) {
  constexpr int FM = BM / (WM * 16);
  constexpr int FN = BN / (WN * 16);
  constexpr int NL = BM / 32 + BN / 32;   // global_load_lds per wave per stage
  static_assert(NL == 8 || NL == 6, "vmcnt literal");
  __shared__ __align__(16) u16 As[2][BM * 64];
  __shared__ __align__(16) u16 Bs[2][BN * 64];
  const int tid = threadIdx.x;
  const int lane = tid & 63, wid = tid >> 6;
  const int wr = wid / WN, wc = wid % WN;
  const int gx = gridDim.x;
  const int lid = blockIdx.y * gx + blockIdx.x;
  const int chunk = (gx * gridDim.y) >> 3;
  const int nid = (lid & 7) * chunk + (lid >> 3);
  const int bx = nid % gx, by = nid / gx;
  const int r0 = by * BM, o0 = bx * BN;
  const int lrow = tid >> 3;                             // 0..31
  const int lce = ((tid & 7) ^ ((tid >> 3) & 7)) << 3;   // swizzled src chunk

  auto STAGE = [&](int buf, int kAs, int k0s) {
#pragma unroll
    for (int i = 0; i < BM / 32; ++i) {
      const u16* srcA = A + (size_t)(r0 + i * 32 + lrow) * AW + kAs + lce;
      __builtin_amdgcn_global_load_lds(
          (const __attribute__((address_space(1))) void*)srcA,
          (__attribute__((address_space(3))) void*)&As[buf][(i * 256 + (wid << 6)) * 8],
          16, 0, 0);
    }
#pragma unroll
    for (int i = 0; i < BN / 32; ++i) {
      const u16* srcB = W2 + (size_t)(o0 + i * 32 + lrow) * K2 + k0s + lce;
      __builtin_amdgcn_global_load_lds(
          (const __attribute__((address_space(1))) void*)srcB,
          (__attribute__((address_space(3))) void*)&Bs[buf][(i * 256 + (wid << 6)) * 8],
          16, 0, 0);
    }
  };

  float4v acc[FM][FN] = {};
  STAGE(0, 0, 0);
  int kA = 0, cur = 0;
  for (int k0 = 0; k0 < K2; k0 += 64) {
    const int kAn = (kA + 64) & (AW - 1);
    if (k0 + 64 < K2) {
      STAGE(cur ^ 1, kAn, k0 + 64);
      if constexpr (NL == 8)
        asm volatile("s_waitcnt vmcnt(8)\n\ts_barrier" ::: "memory");
      else
        asm volatile("s_waitcnt vmcnt(6)\n\ts_barrier" ::: "memory");
    } else {
      asm volatile("s_waitcnt vmcnt(0)\n\ts_barrier" ::: "memory");
    }
#pragma unroll
    for (int kk = 0; kk < 2; ++kk) {
      h8 a[FM], b[FN];
      const int ch0 = (kk << 2) + (lane >> 4);
      const int chs = ch0 ^ (lane & 7);
#pragma unroll
      for (int m = 0; m < FM; ++m) {
        const int R = wr * (FM * 16) + m * 16 + (lane & 15);
        a[m] = *(const h8*)&As[cur][R * 64 + chs * 8];
      }
#pragma unroll
      for (int n = 0; n < FN; ++n) {
        const int Rb = wc * (FN * 16) + n * 16 + (lane & 15);
        b[n] = *(const h8*)&Bs[cur][Rb * 64 + chs * 8];
      }
#pragma unroll
      for (int m = 0; m < FM; ++m)
#pragma unroll
        for (int n = 0; n < FN; ++n)
          acc[m][n] = __builtin_amdgcn_mfma_f32_16x16x32_f16(a[m], b[n], acc[m][n], 0, 0, 0);
    }
    asm volatile("s_waitcnt lgkmcnt(0)\n\ts_barrier" ::: "memory");
    kA = kAn; cur ^= 1;
  }
  const int crow = (lane >> 4) << 2, ccol = lane & 15;
#pragma unroll
  for (int m = 0; m < FM; ++m)
#pragma unroll
    for (int n = 0; n < FN; ++n)
#pragma unroll
      for (int j = 0; j < 4; ++j) {
        const size_t idx =
            (size_t)(r0 + wr * (FM * 16) + (m << 4) + crow + j) * O +
            o0 + wc * (FN * 16) + (n << 4) + ccol;
        float v = acc[m][n][j];
        if (resid) v += resid[idx];
        Y[idx] = v;
      }
  if (STATS) {
    float s1[FN], s2[FN];
#pragma unroll
    for (int n = 0; n < FN; ++n) {
      s1[n] = 0.f; s2[n] = 0.f;
#pragma unroll
      for (int m = 0; m < FM; ++m)
#pragma unroll
        for (int j = 0; j < 4; ++j) {
          const float v = acc[m][n][j];
          s1[n] += v; s2[n] += v * v;
        }
    }
#pragma unroll
    for (int n = 0; n < FN; ++n) {
      s1[n] += __shfl_xor(s1[n], 16); s1[n] += __shfl_xor(s1[n], 32);
      s2[n] += __shfl_xor(s2[n], 16); s2[n] += __shfl_xor(s2[n], 32);
    }
    float* sb = (float*)As;
    __syncthreads();
    if (lane < 16) {
#pragma unroll
      for (int n = 0; n < FN; ++n) {
        const int cl = wc * (FN * 16) + n * 16 + lane;
        sb[wr * BN + cl] = s1[n];
        sb[WM * BN + wr * BN + cl] = s2[n];
      }
    }
    __syncthreads();
    if (tid < BN) {
      float a = 0.f, b = 0.f;
#pragma unroll
      for (int w = 0; w < WM; ++w) {
        a += sb[w * BN + tid];
        b += sb[WM * BN + w * BN + tid];
      }
      p1[(size_t)by * O + o0 + tid] = a;
      p2[(size_t)by * O + o0 + tid] = b;
    }
  }
}

// ---------------------------------------------------------------------------
// BN stats pass 2 (parallel): one block per 64 channels; 4 waves split the
// panel dim; coalesced lane-per-channel reads; LDS reduce (fixed order).
__global__ __launch_bounds__(256) void bn_stats2(const float* __restrict__ p1,
    const float* __restrict__ p2, float* __restrict__ mu,
    float* __restrict__ rinv, int O, int npanels) {
  const int c0 = blockIdx.x << 6;
  const int c = threadIdx.x & 63;
  const int jg = threadIdx.x >> 6;   // 0..3
  float s1 = 0.f, s2 = 0.f;
#pragma unroll 4
  for (int j = jg; j < npanels; j += 4) {
    s1 += p1[(size_t)j * O + c0 + c];
    s2 += p2[(size_t)j * O + c0 + c];
  }
  __shared__ float sb[8][64];
  sb[jg][c] = s1;
  sb[4 + jg][c] = s2;
  __syncthreads();
  if (threadIdx.x < 64) {
    const float a = ((sb[0][c] + sb[1][c]) + (sb[2][c] + sb[3][c]));
    const float b = ((sb[4][c] + sb[5][c]) + (sb[6][c] + sb[7][c]));
    const float m = a * (1.0f / 16384.f);
    const float v = b * (1.0f / 16384.f) - m * m;
    mu[c0 + c] = m;
    rinv[c0 + c] = 1.0f / sqrtf(v + 1e-5f);
  }
}

// Fused QKV BN + spike: Yq is R x 768 = [q|k|v] channels; writes 3 spike bufs.
__global__ __launch_bounds__(256) void qkv_spike(const float* __restrict__ Yq,
    const float* __restrict__ mu, const float* __restrict__ rinv,
    const float* __restrict__ qg, const float* __restrict__ qb,
    const float* __restrict__ kg, const float* __restrict__ kb,
    const float* __restrict__ vg, const float* __restrict__ vb,
    u16* __restrict__ qs, u16* __restrict__ ks, u16* __restrict__ vs) {
  const int i = blockIdx.x * 256 + threadIdx.x;  // float4 id over R*192
  const int r = i / 192, c4 = i - r * 192;
  const int c = c4 << 2;
  const int sel = c >> 8, cc = c & 255;
  const float4 y = ((const float4*)Yq)[i];
  const float4 m4 = *(const float4*)(mu + c);
  const float4 r4 = *(const float4*)(rinv + c);
  const float* g = (sel == 0) ? qg : (sel == 1) ? kg : vg;
  const float* b = (sel == 0) ? qb : (sel == 1) ? kb : vb;
  const float4 g4 = *(const float4*)(g + cc);
  const float4 b4 = *(const float4*)(b + cc);
  ushort4 s;
  s.x = ((y.x - m4.x) * r4.x * g4.x + b4.x >= 1.0f) ? (u16)0x3C00 : (u16)0;
  s.y = ((y.y - m4.y) * r4.y * g4.y + b4.y >= 1.0f) ? (u16)0x3C00 : (u16)0;
  s.z = ((y.z - m4.z) * r4.z * g4.z + b4.z >= 1.0f) ? (u16)0x3C00 : (u16)0;
  s.w = ((y.w - m4.w) * r4.w * g4.w + b4.w >= 1.0f) ? (u16)0x3C00 : (u16)0;
  u16* dst = ((sel == 0) ? qs : (sel == 1) ? ks : vs) + (size_t)r * 256 + cc;
  *(ushort4*)dst = s;
}

// BN affine + Heaviside spike -> f16 spikes {0, 0x3C00}.
__global__ __launch_bounds__(256) void bn_spike_f16(const float* __restrict__ Y,
    const float* __restrict__ mu, const float* __restrict__ rinv,
    const float* __restrict__ g, const float* __restrict__ b,
    u16* __restrict__ S, int O) {
  const int i = blockIdx.x * 256 + threadIdx.x;
  const int c = (i << 2) & (O - 1);
  const float4 y = ((const float4*)Y)[i];
  const float4 m4 = *(const float4*)(mu + c);
  const float4 r4 = *(const float4*)(rinv + c);
  const float4 g4 = *(const float4*)(g + c);
  const float4 b4 = *(const float4*)(b + c);
  ushort4 s;
  s.x = ((y.x - m4.x) * r4.x * g4.x + b4.x >= 1.0f) ? (u16)0x3C00 : (u16)0;
  s.y = ((y.y - m4.y) * r4.y * g4.y + b4.y >= 1.0f) ? (u16)0x3C00 : (u16)0;
  s.z = ((y.z - m4.z) * r4.z * g4.z + b4.z >= 1.0f) ? (u16)0x3C00 : (u16)0;
  s.w = ((y.w - m4.w) * r4.w * g4.w + b4.w >= 1.0f) ? (u16)0x3C00 : (u16)0;
  ((ushort4*)S)[i] = s;
}

// BN affine + spike added into fp32 output (final residual).
__global__ __launch_bounds__(256) void bn_spike_add(const float* __restrict__ Y,
    const float* __restrict__ mu, const float* __restrict__ rinv,
    const float* __restrict__ g, const float* __restrict__ b,
    float* __restrict__ addOut, int O) {
  const int i = blockIdx.x * 256 + threadIdx.x;
  const int c = (i << 2) & (O - 1);
  const float4 y = ((const float4*)Y)[i];
  const float4 m4 = *(const float4*)(mu + c);
  const float4 r4 = *(const float4*)(rinv + c);
  const float4 g4 = *(const float4*)(g + c);
  const float4 b4 = *(const float4*)(b + c);
  float4 o4 = ((const float4*)addOut)[i];
  o4.x += ((y.x - m4.x) * r4.x * g4.x + b4.x >= 1.0f) ? 1.0f : 0.0f;
  o4.y += ((y.y - m4.y) * r4.y * g4.y + b4.y >= 1.0f) ? 1.0f : 0.0f;
  o4.z += ((y.z - m4.z) * r4.z * g4.z + b4.z >= 1.0f) ? 1.0f : 0.0f;
  o4.w += ((y.w - m4.w) * r4.w * g4.w + b4.w >= 1.0f) ? 1.0f : 0.0f;
  ((float4*)addOut)[i] = o4;
}

// ---------------------------------------------------------------------------
// M[b,h] = K^T V (64x64), split over n into 16 partials. Inputs: f16 spikes.
__global__ __launch_bounds__(256) void attn_kv(const u16* __restrict__ Ksp,
    const u16* __restrict__ Vsp, float* __restrict__ Mpart) {
  const int bh = blockIdx.x, sp = blockIdx.y;
  const int b = bh >> 2, h = bh & 3;
  const int t = threadIdx.x;
  const int gq = t >> 6, e = t & 63;
  const size_t base = (size_t)b * NN * CC + (h << 6);
  __shared__ float ks[16][64], vs[16][64];
  float acc[16] = {};
  const int lrow = t >> 4, lf = (t & 15) << 2;
  for (int n0 = sp * 128; n0 < sp * 128 + 128; n0 += 16) {
    const ushort4 kq = *(const ushort4*)(Ksp + base + (size_t)(n0 + lrow) * CC + lf);
    const ushort4 vq = *(const ushort4*)(Vsp + base + (size_t)(n0 + lrow) * CC + lf);
    __syncthreads();
    ks[lrow][lf + 0] = h2f(kq.x); ks[lrow][lf + 1] = h2f(kq.y);
    ks[lrow][lf + 2] = h2f(kq.z); ks[lrow][lf + 3] = h2f(kq.w);
    vs[lrow][lf + 0] = h2f(vq.x); vs[lrow][lf + 1] = h2f(vq.y);
    vs[lrow][lf + 2] = h2f(vq.z); vs[lrow][lf + 3] = h2f(vq.w);
    __syncthreads();
#pragma unroll
    for (int nn = 0; nn < 16; ++nn) {
      const float vv = vs[nn][e];
#pragma unroll
      for (int i = 0; i < 16; ++i) acc[i] += ks[nn][(gq << 4) + i] * vv;
    }
  }
  float* mp = Mpart + ((size_t)bh * 16 + sp) * 4096;
#pragma unroll
  for (int i = 0; i < 16; ++i) mp[((gq << 4) + i) * 64 + e] = acc[i];
}

__global__ __launch_bounds__(256) void attn_kv_reduce(
    const float* __restrict__ Mpart, float* __restrict__ M) {
  const int i = blockIdx.x * 256 + threadIdx.x;
  const int bh = i >> 12, j = i & 4095;
  float s = 0.f;
#pragma unroll
  for (int sp = 0; sp < 16; ++sp)
    s += Mpart[((size_t)bh * 16 + sp) * 4096 + j];
  M[i] = s;
}

// o = 0.125 * q @ M (exact), written as EXACT 2-term f16 [o1|o2] (width 512).
__global__ __launch_bounds__(256) void attn_qm(const u16* __restrict__ Qsp,
    const float* __restrict__ M, u16* __restrict__ O2) {
  const int h = blockIdx.x;
  const int r0 = blockIdx.y << 6;
  const int b = blockIdx.y >> 5;
  const int t = threadIdx.x;
  const int e = t & 63, rg = t >> 6;
  __shared__ float Ms[64][64];
  __shared__ float qs[64][64];
  const float* Mb = M + ((size_t)(b * 4 + h) << 12);
  for (int i = t; i < 4096; i += 256) ((float*)Ms)[i] = Mb[i];
  for (int rl = rg; rl < 64; rl += 4)
    qs[rl][e] = h2f(Qsp[(size_t)(r0 + rl) * CC + (h << 6) + e]);
  __syncthreads();
  for (int rl = rg; rl < 64; rl += 4) {
    float acc = 0.f;
#pragma unroll
    for (int d = 0; d < 64; ++d) acc += qs[rl][d] * Ms[d][e];
    const float o = 0.125f * acc;   // exact multiple of 1/8
    const u16 hi = f2h(o);
    const u16 lo = f2h(o - h2f(hi));  // exact 2-term
    O2[(size_t)(r0 + rl) * 512 + (h << 6) + e] = hi;
    O2[(size_t)(r0 + rl) * 512 + 256 + (h << 6) + e] = lo;
  }
}

// ---------------------------------------------------------------------------
extern "C" void kernel_launch(void* const* d_in, const int* in_sizes, int n_in,
                              void* d_out, int out_size, void* d_ws,
                              size_t ws_size, hipStream_t stream) {
  const float* x    = (const float*)d_in[0];
  const float* ln1g = (const float*)d_in[1];
  const float* ln1b = (const float*)d_in[2];
  const float* wq   = (const float*)d_in[3];
  const float* qg   = (const float*)d_in[4];
  const float* qb   = (const float*)d_in[5];
  const float* wk   = (const float*)d_in[6];
  const float* kg   = (const float*)d_in[7];
  const float* kb   = (const float*)d_in[8];
  const float* wv   = (const float*)d_in[9];
  const float* vg   = (const float*)d_in[10];
  const float* vb   = (const float*)d_in[11];
  const float* wo   = (const float*)d_in[12];
  const float* ln2g = (const float*)d_in[13];
  const float* ln2b = (const float*)d_in[14];
  const float* w1   = (const float*)d_in[15];
  const float* b1g  = (const float*)d_in[16];
  const float* b1b  = (const float*)d_in[17];
  const float* w2   = (const float*)d_in[18];
  const float* b2g  = (const float*)d_in[19];
  const float* b2b  = (const float*)d_in[20];
  float* out = (float*)d_out;
  char* ws = (char*)d_ws;
  const size_t MB = 1u << 20;
  u16*   h1s   = (u16*)(ws);               // [0,16)   dead after QKV gemm
  float* Yq    = (float*)(ws + 16 * MB);   // [16,64)  R x 768 fp32
  u16*   qs_   = (u16*)(ws + 64 * MB);     // [64,72)
  u16*   ks_   = (u16*)(ws + 72 * MB);     // [72,80)
  u16*   vs_   = (u16*)(ws + 80 * MB);     // [80,88)
  float* Mpart = (float*)(ws + 88 * MB);   // [88,96)  8 MB
  float* Mful  = (float*)(ws + 96 * MB);   // [96,96.5)
  u16*   o2    = (u16*)(ws);               // [0,16)   overlays h1s (dead)
  u16*   h2s   = (u16*)(ws + 16 * MB);     // [16,32)  overlays Yq-lo (dead)
  float* Ym    = (float*)(ws + 32 * MB);   // [32,96)  R x 1024 fp32 (MLP)
  u16*   m1    = (u16*)(ws + 97 * MB);     // [97,129) R x 1024 f16
  u16*   Wqkv  = (u16*)(ws + 129 * MB);    // 768 x 768 f16 = 1.125 MB
  u16*   wo2   = (u16*)(ws + 131 * MB);    // 256 x 768 f16 = 384 KB
  u16*   w12   = (u16*)(ws + 132 * MB);    // 1024 x 768 f16 = 1.5 MB
  u16*   w22   = (u16*)(ws + 134 * MB);    // 256 x 2048 f16 = 1 MB
  float* p1    = (float*)(ws + 135 * MB);  // 1 MB (npanels x O)
  float* p2    = (float*)(ws + 136 * MB);  // 1 MB
  float* mu    = (float*)(ws + 137 * MB);
  float* rinv  = (float*)(ws + 137 * MB + 32768);

  const dim3 blk(256);

  // Weight splits, one dispatch
  split_all<<<3072, blk, 0, stream>>>(wq, wk, wv, wo, w1, w2, Wqkv, wo2, w12, w22);

  // 1. h1 = LN1(x) -> split f16
  ln_split<<<RR / 4, blk, 0, stream>>>(x, ln1g, ln1b, h1s);

  // 2. Fused QKV projection (MFMA, O=768, K'=768) + fused BN pass-1
  gemm_sp<128, 128, 2, 2, 1><<<dim3(6, 128), blk, 0, stream>>>(
      h1s, 512, Wqkv, 768, nullptr, Yq, 768, p1, p2);

  // 3. BN stats finalize + spike for q|k|v
  bn_stats2<<<12, blk, 0, stream>>>(p1, p2, mu, rinv, 768, 128);
  qkv_spike<<<RR * 192 / 256, blk, 0, stream>>>(Yq, mu, rinv, qg, qb, kg, kb,
                                                vg, vb, qs_, ks_, vs_);

  // 4-6. attention: M = K^T V (exact int), o = 0.125 q@M -> exact 2-term f16
  attn_kv<<<dim3(32, 16), blk, 0, stream>>>(ks_, vs_, Mpart);
  attn_kv_reduce<<<512, blk, 0, stream>>>(Mpart, Mful);
  attn_qm<<<dim3(4, RR / 64), blk, 0, stream>>>(qs_, Mful, o2);

  // 7. x2 = x + o @ wo^T -> out   (MFMA, 3-term, K'=768)
  gemm_sp<64, 128, 2, 2, 0><<<dim3(2, 256), blk, 0, stream>>>(
      o2, 512, wo2, 768, x, out, 256, nullptr, nullptr);

  // 8. h2 = LN2(x2) -> split f16
  ln_split<<<RR / 4, blk, 0, stream>>>(out, ln2g, ln2b, h2s);

  // 9-10. MLP1 (3-term, K'=768) + fused BN pass-1 + spike -> m1
  gemm_sp<128, 128, 2, 2, 1><<<dim3(8, 128), blk, 0, stream>>>(
      h2s, 512, w12, 768, nullptr, Ym, 1024, p1, p2);
  bn_stats2<<<16, blk, 0, stream>>>(p1, p2, mu, rinv, 1024, 128);
  bn_spike_f16<<<16384, blk, 0, stream>>>(Ym, mu, rinv, b1g, b1b, m1, 1024);

  // 11-12. MLP2 (binary-exact A x 2-term W, K'=2048) + BN + spike-add
  gemm_sp<64, 128, 2, 2, 1><<<dim3(2, 256), blk, 0, stream>>>(
      m1, 1024, w22, 2048, nullptr, Ym, 256, p1, p2);
  bn_stats2<<<4, blk, 0, stream>>>(p1, p2, mu, rinv, 256, 256);
  bn_spike_add<<<4096, blk, 0, stream>>>(Ym, mu, rinv, b2g, b2b, out, 256);
}

// Round 8
// 225.481 us; speedup vs baseline: 1.8287x; 1.0939x over previous
//
#include <hip/hip_runtime.h>
#include <cstddef>
#include <cstdint>

#define RR 16384   // B*N rows
#define CC 256
#define NN 2048

typedef __attribute__((ext_vector_type(8))) _Float16 h8;
typedef __attribute__((ext_vector_type(4))) float float4v;
typedef unsigned short u16;

__device__ inline float h2f(u16 u) {
  return (float)__builtin_bit_cast(_Float16, u);
}
__device__ inline u16 f2h(float f) {
  return __builtin_bit_cast(u16, (_Float16)f);
}

// ---------------------------------------------------------------------------
// LayerNorm -> split f16 [hi(256) | lo(256)] per row.
__global__ __launch_bounds__(256) void ln_split(const float* __restrict__ x,
    const float* __restrict__ g, const float* __restrict__ b,
    u16* __restrict__ out) {
  const int wave = threadIdx.x >> 6, lane = threadIdx.x & 63;
  const int row = (blockIdx.x << 2) + wave;
  const float4 v = ((const float4*)(x + (size_t)row * CC))[lane];
  float s1 = v.x + v.y + v.z + v.w;
  float s2 = v.x * v.x + v.y * v.y + v.z * v.z + v.w * v.w;
#pragma unroll
  for (int o = 32; o > 0; o >>= 1) {
    s1 += __shfl_xor(s1, o);
    s2 += __shfl_xor(s2, o);
  }
  const float mu = s1 * (1.0f / CC);
  const float var = s2 * (1.0f / CC) - mu * mu;
  const float rs = 1.0f / sqrtf(var + 1e-5f);
  const float4 gg = ((const float4*)g)[lane];
  const float4 bb = ((const float4*)b)[lane];
  float o4[4];
  o4[0] = (v.x - mu) * rs * gg.x + bb.x;
  o4[1] = (v.y - mu) * rs * gg.y + bb.y;
  o4[2] = (v.z - mu) * rs * gg.z + bb.z;
  o4[3] = (v.w - mu) * rs * gg.w + bb.w;
  ushort4 hi, lo;
  hi.x = f2h(o4[0]); lo.x = f2h(o4[0] - h2f(hi.x));
  hi.y = f2h(o4[1]); lo.y = f2h(o4[1] - h2f(hi.y));
  hi.z = f2h(o4[2]); lo.z = f2h(o4[2] - h2f(hi.z));
  hi.w = f2h(o4[3]); lo.w = f2h(o4[3] - h2f(hi.w));
  *(ushort4*)(out + (size_t)row * 512 + (lane << 2)) = hi;
  *(ushort4*)(out + (size_t)row * 512 + 256 + (lane << 2)) = lo;
}

// ---------------------------------------------------------------------------
// All weight splits in ONE dispatch (3072 blocks).
// 3-term layout [W1|W1|W2] (width 3K) pairs cyclic A=[hi|lo] (AW=2K):
//   products hi*W1 + lo*W1 + hi*W2 (drops lo*W2 ~ 2^-22 rel).
__global__ __launch_bounds__(256) void split_all(const float* __restrict__ wq,
    const float* __restrict__ wk, const float* __restrict__ wv,
    const float* __restrict__ wo, const float* __restrict__ w1,
    const float* __restrict__ w2, u16* __restrict__ Wqkv,
    u16* __restrict__ wo2, u16* __restrict__ w12, u16* __restrict__ w22) {
  const int bid = blockIdx.x;
  if (bid < 2048) {  // 3-term splits, K=256
    const float* W; u16* D; int rowoff; int li;
    if (bid < 768) {
      W = (bid < 256) ? wq : (bid < 512) ? wk : wv;
      D = Wqkv; rowoff = (bid >> 8) << 8;
      li = (bid & 255) * 256 + threadIdx.x;
    } else if (bid < 1024) {
      W = wo; D = wo2; rowoff = 0;
      li = (bid - 768) * 256 + threadIdx.x;
    } else {
      W = w1; D = w12; rowoff = 0;
      li = (bid - 1024) * 256 + threadIdx.x;
    }
    const int o = li >> 8, k = li & 255;
    const float w = W[li];
    const u16 h1 = f2h(w);
    const u16 h2 = f2h(w - h2f(h1));
    u16* base = D + (size_t)(o + rowoff) * 768;
    base[k] = h1; base[256 + k] = h1; base[512 + k] = h2;
  } else {  // w2 2-term, K=1024
    const int li = (bid - 2048) * 256 + threadIdx.x;
    const int o = li >> 10, k = li & 1023;
    const float w = w2[li];
    const u16 h1 = f2h(w);
    const u16 h2 = f2h(w - h2f(h1));
    u16* base = w22 + (size_t)o * 2048;
    base[k] = h1; base[1024 + k] = h2;
  }
}

// ---------------------------------------------------------------------------
// MFMA f16 GEMM, 8 waves (512 threads), 2-phase double-buffered pipeline.
// Y[r,o] = sum_{k'} A[r, k' mod AW] * W2[o, k']  (+resid)
// Tile BM x BN, BK=64, waves WM x WN (=8), mfma_f32_16x16x32_f16.
// T2 LDS swizzle both-sides; T1 XCD-aware block swizzle (nwg % 8 == 0).
// STATS: fused BN pass-1 per row-panel into p1/p2[by*O + col].
template <int BM, int BN, int WM, int WN, int STATS>
__global__ __launch_bounds__(512, 4) void gemm_sp(
    const u16* __restrict__ A, int AW,
    const u16* __restrict__ W2, int K2,
    const float* __restrict__ resid, float* __restrict__ Y, int O,
    float* __restrict__ p1, float* __restrict__ p2) {
  constexpr int FM = BM / (WM * 16);
  constexpr int FN = BN / (WN * 16);
  constexpr int LA = BM / 64;             // A stage lines (8KB each)
  constexpr int LB = BN / 64;             // B stage lines
  constexpr int NL = LA + LB;             // loads in flight per wave per stage
  static_assert(WM * WN == 8, "8 waves");
  static_assert(NL == 3 || NL == 4 || NL == 5, "vmcnt literal");
  __shared__ __align__(16) u16 As[2][BM * 64];
  __shared__ __align__(16) u16 Bs[2][BN * 64];
  const int tid = threadIdx.x;
  const int lane = tid & 63, wid = tid >> 6;
  const int wr = wid / WN, wc = wid % WN;
  const int gx = gridDim.x;
  const int lid = blockIdx.y * gx + blockIdx.x;
  const int chunk = (gx * gridDim.y) >> 3;
  const int nid = (lid & 7) * chunk + (lid >> 3);
  const int bx = nid % gx, by = nid / gx;
  const int r0 = by * BM, o0 = bx * BN;
  const int lrow = tid >> 3;                             // 0..63
  const int lce = ((tid & 7) ^ ((tid >> 3) & 7)) << 3;   // swizzled src chunk

  auto STAGE = [&](int buf, int kAs, int k0s) {
#pragma unroll
    for (int i = 0; i < LA; ++i) {
      const u16* srcA = A + (size_t)(r0 + i * 64 + lrow) * AW + kAs + lce;
      __builtin_amdgcn_global_load_lds(
          (const __attribute__((address_space(1))) void*)srcA,
          (__attribute__((address_space(3))) void*)&As[buf][(i * 64 + wid * 8) * 64],
          16, 0, 0);
    }
#pragma unroll
    for (int i = 0; i < LB; ++i) {
      const u16* srcB = W2 + (size_t)(o0 + i * 64 + lrow) * K2 + k0s + lce;
      __builtin_amdgcn_global_load_lds(
          (const __attribute__((address_space(1))) void*)srcB,
          (__attribute__((address_space(3))) void*)&Bs[buf][(i * 64 + wid * 8) * 64],
          16, 0, 0);
    }
  };

  float4v acc[FM][FN] = {};
  STAGE(0, 0, 0);
  int kA = 0, cur = 0;
  for (int k0 = 0; k0 < K2; k0 += 64) {
    const int kAn = (kA + 64) & (AW - 1);
    if (k0 + 64 < K2) {
      STAGE(cur ^ 1, kAn, k0 + 64);
      if constexpr (NL == 3)
        asm volatile("s_waitcnt vmcnt(3)\n\ts_barrier" ::: "memory");
      else if constexpr (NL == 4)
        asm volatile("s_waitcnt vmcnt(4)\n\ts_barrier" ::: "memory");
      else
        asm volatile("s_waitcnt vmcnt(5)\n\ts_barrier" ::: "memory");
    } else {
      asm volatile("s_waitcnt vmcnt(0)\n\ts_barrier" ::: "memory");
    }
#pragma unroll
    for (int kk = 0; kk < 2; ++kk) {
      h8 a[FM], b[FN];
      const int ch0 = (kk << 2) + (lane >> 4);
      const int chs = ch0 ^ (lane & 7);
#pragma unroll
      for (int m = 0; m < FM; ++m) {
        const int R = wr * (FM * 16) + m * 16 + (lane & 15);
        a[m] = *(const h8*)&As[cur][R * 64 + chs * 8];
      }
#pragma unroll
      for (int n = 0; n < FN; ++n) {
        const int Rb = wc * (FN * 16) + n * 16 + (lane & 15);
        b[n] = *(const h8*)&Bs[cur][Rb * 64 + chs * 8];
      }
#pragma unroll
      for (int m = 0; m < FM; ++m)
#pragma unroll
        for (int n = 0; n < FN; ++n)
          acc[m][n] = __builtin_amdgcn_mfma_f32_16x16x32_f16(a[m], b[n], acc[m][n], 0, 0, 0);
    }
    asm volatile("s_waitcnt lgkmcnt(0)\n\ts_barrier" ::: "memory");
    kA = kAn; cur ^= 1;
  }
  const int crow = (lane >> 4) << 2, ccol = lane & 15;
#pragma unroll
  for (int m = 0; m < FM; ++m)
#pragma unroll
    for (int n = 0; n < FN; ++n)
#pragma unroll
      for (int j = 0; j < 4; ++j) {
        const size_t idx =
            (size_t)(r0 + wr * (FM * 16) + (m << 4) + crow + j) * O +
            o0 + wc * (FN * 16) + (n << 4) + ccol;
        float v = acc[m][n][j];
        if (resid) v += resid[idx];
        Y[idx] = v;
      }
  if (STATS) {
    float s1[FN], s2[FN];
#pragma unroll
    for (int n = 0; n < FN; ++n) {
      s1[n] = 0.f; s2[n] = 0.f;
#pragma unroll
      for (int m = 0; m < FM; ++m)
#pragma unroll
        for (int j = 0; j < 4; ++j) {
          const float v = acc[m][n][j];
          s1[n] += v; s2[n] += v * v;
        }
    }
#pragma unroll
    for (int n = 0; n < FN; ++n) {
      s1[n] += __shfl_xor(s1[n], 16); s1[n] += __shfl_xor(s1[n], 32);
      s2[n] += __shfl_xor(s2[n], 16); s2[n] += __shfl_xor(s2[n], 32);
    }
    float* sb = (float*)As;
    __syncthreads();
    if (lane < 16) {
#pragma unroll
      for (int n = 0; n < FN; ++n) {
        const int cl = wc * (FN * 16) + n * 16 + lane;
        sb[wr * BN + cl] = s1[n];
        sb[WM * BN + wr * BN + cl] = s2[n];
      }
    }
    __syncthreads();
    if (tid < BN) {
      float a = 0.f, b = 0.f;
#pragma unroll
      for (int w = 0; w < WM; ++w) {
        a += sb[w * BN + tid];
        b += sb[WM * BN + w * BN + tid];
      }
      p1[(size_t)by * O + o0 + tid] = a;
      p2[(size_t)by * O + o0 + tid] = b;
    }
  }
}

// ---------------------------------------------------------------------------
// BN stats pass 2 (parallel): one block per 64 channels; 4 waves split the
// panel dim; coalesced lane-per-channel reads; LDS reduce (fixed order).
__global__ __launch_bounds__(256) void bn_stats2(const float* __restrict__ p1,
    const float* __restrict__ p2, float* __restrict__ mu,
    float* __restrict__ rinv, int O, int npanels) {
  const int c0 = blockIdx.x << 6;
  const int c = threadIdx.x & 63;
  const int jg = threadIdx.x >> 6;   // 0..3
  float s1 = 0.f, s2 = 0.f;
#pragma unroll 4
  for (int j = jg; j < npanels; j += 4) {
    s1 += p1[(size_t)j * O + c0 + c];
    s2 += p2[(size_t)j * O + c0 + c];
  }
  __shared__ float sb[8][64];
  sb[jg][c] = s1;
  sb[4 + jg][c] = s2;
  __syncthreads();
  if (threadIdx.x < 64) {
    const float a = ((sb[0][c] + sb[1][c]) + (sb[2][c] + sb[3][c]));
    const float b = ((sb[4][c] + sb[5][c]) + (sb[6][c] + sb[7][c]));
    const float m = a * (1.0f / 16384.f);
    const float v = b * (1.0f / 16384.f) - m * m;
    mu[c0 + c] = m;
    rinv[c0 + c] = 1.0f / sqrtf(v + 1e-5f);
  }
}

// Fused QKV BN + spike: Yq is R x 768 = [q|k|v] channels; writes 3 spike bufs.
__global__ __launch_bounds__(256) void qkv_spike(const float* __restrict__ Yq,
    const float* __restrict__ mu, const float* __restrict__ rinv,
    const float* __restrict__ qg, const float* __restrict__ qb,
    const float* __restrict__ kg, const float* __restrict__ kb,
    const float* __restrict__ vg, const float* __restrict__ vb,
    u16* __restrict__ qs, u16* __restrict__ ks, u16* __restrict__ vs) {
  const int i = blockIdx.x * 256 + threadIdx.x;  // float4 id over R*192
  const int r = i / 192, c4 = i - r * 192;
  const int c = c4 << 2;
  const int sel = c >> 8, cc = c & 255;
  const float4 y = ((const float4*)Yq)[i];
  const float4 m4 = *(const float4*)(mu + c);
  const float4 r4 = *(const float4*)(rinv + c);
  const float* g = (sel == 0) ? qg : (sel == 1) ? kg : vg;
  const float* b = (sel == 0) ? qb : (sel == 1) ? kb : vb;
  const float4 g4 = *(const float4*)(g + cc);
  const float4 b4 = *(const float4*)(b + cc);
  ushort4 s;
  s.x = ((y.x - m4.x) * r4.x * g4.x + b4.x >= 1.0f) ? (u16)0x3C00 : (u16)0;
  s.y = ((y.y - m4.y) * r4.y * g4.y + b4.y >= 1.0f) ? (u16)0x3C00 : (u16)0;
  s.z = ((y.z - m4.z) * r4.z * g4.z + b4.z >= 1.0f) ? (u16)0x3C00 : (u16)0;
  s.w = ((y.w - m4.w) * r4.w * g4.w + b4.w >= 1.0f) ? (u16)0x3C00 : (u16)0;
  u16* dst = ((sel == 0) ? qs : (sel == 1) ? ks : vs) + (size_t)r * 256 + cc;
  *(ushort4*)dst = s;
}

// BN affine + Heaviside spike -> f16 spikes {0, 0x3C00}.
__global__ __launch_bounds__(256) void bn_spike_f16(const float* __restrict__ Y,
    const float* __restrict__ mu, const float* __restrict__ rinv,
    const float* __restrict__ g, const float* __restrict__ b,
    u16* __restrict__ S, int O) {
  const int i = blockIdx.x * 256 + threadIdx.x;
  const int c = (i << 2) & (O - 1);
  const float4 y = ((const float4*)Y)[i];
  const float4 m4 = *(const float4*)(mu + c);
  const float4 r4 = *(const float4*)(rinv + c);
  const float4 g4 = *(const float4*)(g + c);
  const float4 b4 = *(const float4*)(b + c);
  ushort4 s;
  s.x = ((y.x - m4.x) * r4.x * g4.x + b4.x >= 1.0f) ? (u16)0x3C00 : (u16)0;
  s.y = ((y.y - m4.y) * r4.y * g4.y + b4.y >= 1.0f) ? (u16)0x3C00 : (u16)0;
  s.z = ((y.z - m4.z) * r4.z * g4.z + b4.z >= 1.0f) ? (u16)0x3C00 : (u16)0;
  s.w = ((y.w - m4.w) * r4.w * g4.w + b4.w >= 1.0f) ? (u16)0x3C00 : (u16)0;
  ((ushort4*)S)[i] = s;
}

// BN affine + spike added into fp32 output (final residual).
__global__ __launch_bounds__(256) void bn_spike_add(const float* __restrict__ Y,
    const float* __restrict__ mu, const float* __restrict__ rinv,
    const float* __restrict__ g, const float* __restrict__ b,
    float* __restrict__ addOut, int O) {
  const int i = blockIdx.x * 256 + threadIdx.x;
  const int c = (i << 2) & (O - 1);
  const float4 y = ((const float4*)Y)[i];
  const float4 m4 = *(const float4*)(mu + c);
  const float4 r4 = *(const float4*)(rinv + c);
  const float4 g4 = *(const float4*)(g + c);
  const float4 b4 = *(const float4*)(b + c);
  float4 o4 = ((const float4*)addOut)[i];
  o4.x += ((y.x - m4.x) * r4.x * g4.x + b4.x >= 1.0f) ? 1.0f : 0.0f;
  o4.y += ((y.y - m4.y) * r4.y * g4.y + b4.y >= 1.0f) ? 1.0f : 0.0f;
  o4.z += ((y.z - m4.z) * r4.z * g4.z + b4.z >= 1.0f) ? 1.0f : 0.0f;
  o4.w += ((y.w - m4.w) * r4.w * g4.w + b4.w >= 1.0f) ? 1.0f : 0.0f;
  ((float4*)addOut)[i] = o4;
}

// ---------------------------------------------------------------------------
// M[b,h] = K^T V (64x64), split over n into 16 partials. Inputs: f16 spikes.
__global__ __launch_bounds__(256) void attn_kv(const u16* __restrict__ Ksp,
    const u16* __restrict__ Vsp, float* __restrict__ Mpart) {
  const int bh = blockIdx.x, sp = blockIdx.y;
  const int b = bh >> 2, h = bh & 3;
  const int t = threadIdx.x;
  const int gq = t >> 6, e = t & 63;
  const size_t base = (size_t)b * NN * CC + (h << 6);
  __shared__ float ks[16][64], vs[16][64];
  float acc[16] = {};
  const int lrow = t >> 4, lf = (t & 15) << 2;
  for (int n0 = sp * 128; n0 < sp * 128 + 128; n0 += 16) {
    const ushort4 kq = *(const ushort4*)(Ksp + base + (size_t)(n0 + lrow) * CC + lf);
    const ushort4 vq = *(const ushort4*)(Vsp + base + (size_t)(n0 + lrow) * CC + lf);
    __syncthreads();
    ks[lrow][lf + 0] = h2f(kq.x); ks[lrow][lf + 1] = h2f(kq.y);
    ks[lrow][lf + 2] = h2f(kq.z); ks[lrow][lf + 3] = h2f(kq.w);
    vs[lrow][lf + 0] = h2f(vq.x); vs[lrow][lf + 1] = h2f(vq.y);
    vs[lrow][lf + 2] = h2f(vq.z); vs[lrow][lf + 3] = h2f(vq.w);
    __syncthreads();
#pragma unroll
    for (int nn = 0; nn < 16; ++nn) {
      const float vv = vs[nn][e];
#pragma unroll
      for (int i = 0; i < 16; ++i) acc[i] += ks[nn][(gq << 4) + i] * vv;
    }
  }
  float* mp = Mpart + ((size_t)bh * 16 + sp) * 4096;
#pragma unroll
  for (int i = 0; i < 16; ++i) mp[((gq << 4) + i) * 64 + e] = acc[i];
}

__global__ __launch_bounds__(256) void attn_kv_reduce(
    const float* __restrict__ Mpart, float* __restrict__ M) {
  const int i = blockIdx.x * 256 + threadIdx.x;
  const int bh = i >> 12, j = i & 4095;
  float s = 0.f;
#pragma unroll
  for (int sp = 0; sp < 16; ++sp)
    s += Mpart[((size_t)bh * 16 + sp) * 4096 + j];
  M[i] = s;
}

// o = 0.125 * q @ M (exact), written as EXACT 2-term f16 [o1|o2] (width 512).
__global__ __launch_bounds__(256) void attn_qm(const u16* __restrict__ Qsp,
    const float* __restrict__ M, u16* __restrict__ O2) {
  const int h = blockIdx.x;
  const int r0 = blockIdx.y << 6;
  const int b = blockIdx.y >> 5;
  const int t = threadIdx.x;
  const int e = t & 63, rg = t >> 6;
  __shared__ float Ms[64][64];
  __shared__ float qs[64][64];
  const float* Mb = M + ((size_t)(b * 4 + h) << 12);
  for (int i = t; i < 4096; i += 256) ((float*)Ms)[i] = Mb[i];
  for (int rl = rg; rl < 64; rl += 4)
    qs[rl][e] = h2f(Qsp[(size_t)(r0 + rl) * CC + (h << 6) + e]);
  __syncthreads();
  for (int rl = rg; rl < 64; rl += 4) {
    float acc = 0.f;
#pragma unroll
    for (int d = 0; d < 64; ++d) acc += qs[rl][d] * Ms[d][e];
    const float o = 0.125f * acc;   // exact multiple of 1/8
    const u16 hi = f2h(o);
    const u16 lo = f2h(o - h2f(hi));  // exact 2-term
    O2[(size_t)(r0 + rl) * 512 + (h << 6) + e] = hi;
    O2[(size_t)(r0 + rl) * 512 + 256 + (h << 6) + e] = lo;
  }
}

// ---------------------------------------------------------------------------
extern "C" void kernel_launch(void* const* d_in, const int* in_sizes, int n_in,
                              void* d_out, int out_size, void* d_ws,
                              size_t ws_size, hipStream_t stream) {
  const float* x    = (const float*)d_in[0];
  const float* ln1g = (const float*)d_in[1];
  const float* ln1b = (const float*)d_in[2];
  const float* wq   = (const float*)d_in[3];
  const float* qg   = (const float*)d_in[4];
  const float* qb   = (const float*)d_in[5];
  const float* wk   = (const float*)d_in[6];
  const float* kg   = (const float*)d_in[7];
  const float* kb   = (const float*)d_in[8];
  const float* wv   = (const float*)d_in[9];
  const float* vg   = (const float*)d_in[10];
  const float* vb   = (const float*)d_in[11];
  const float* wo   = (const float*)d_in[12];
  const float* ln2g = (const float*)d_in[13];
  const float* ln2b = (const float*)d_in[14];
  const float* w1   = (const float*)d_in[15];
  const float* b1g  = (const float*)d_in[16];
  const float* b1b  = (const float*)d_in[17];
  const float* w2   = (const float*)d_in[18];
  const float* b2g  = (const float*)d_in[19];
  const float* b2b  = (const float*)d_in[20];
  float* out = (float*)d_out;
  char* ws = (char*)d_ws;
  const size_t MB = 1u << 20;
  u16*   h1s   = (u16*)(ws);               // [0,16)   dead after QKV gemm
  float* Yq    = (float*)(ws + 16 * MB);   // [16,64)  R x 768 fp32
  u16*   qs_   = (u16*)(ws + 64 * MB);     // [64,72)
  u16*   ks_   = (u16*)(ws + 72 * MB);     // [72,80)
  u16*   vs_   = (u16*)(ws + 80 * MB);     // [80,88)
  float* Mpart = (float*)(ws + 88 * MB);   // [88,96)  8 MB
  float* Mful  = (float*)(ws + 96 * MB);   // [96,96.5)
  u16*   o2    = (u16*)(ws);               // [0,16)   overlays h1s (dead)
  u16*   h2s   = (u16*)(ws + 16 * MB);     // [16,32)  overlays Yq-lo (dead)
  float* Ym    = (float*)(ws + 32 * MB);   // [32,96)  R x 1024 fp32 (MLP)
  u16*   m1    = (u16*)(ws + 97 * MB);     // [97,129) R x 1024 f16
  u16*   Wqkv  = (u16*)(ws + 129 * MB);    // 768 x 768 f16 = 1.125 MB
  u16*   wo2   = (u16*)(ws + 131 * MB);    // 256 x 768 f16 = 384 KB
  u16*   w12   = (u16*)(ws + 132 * MB);    // 1024 x 768 f16 = 1.5 MB
  u16*   w22   = (u16*)(ws + 134 * MB);    // 256 x 2048 f16 = 1 MB
  float* p1    = (float*)(ws + 135 * MB);  // 1 MB (npanels x O)
  float* p2    = (float*)(ws + 136 * MB);  // 1 MB
  float* mu    = (float*)(ws + 137 * MB);
  float* rinv  = (float*)(ws + 137 * MB + 32768);

  const dim3 blk(256);
  const dim3 blk512(512);

  // Weight splits, one dispatch
  split_all<<<3072, blk, 0, stream>>>(wq, wk, wv, wo, w1, w2, Wqkv, wo2, w12, w22);

  // 1. h1 = LN1(x) -> split f16
  ln_split<<<RR / 4, blk, 0, stream>>>(x, ln1g, ln1b, h1s);

  // 2. Fused QKV projection (MFMA, O=768, K'=768, grid 512 = 1 full round)
  gemm_sp<128, 192, 2, 4, 1><<<dim3(4, 128), blk512, 0, stream>>>(
      h1s, 512, Wqkv, 768, nullptr, Yq, 768, p1, p2);

  // 3. BN stats finalize + spike for q|k|v
  bn_stats2<<<12, blk, 0, stream>>>(p1, p2, mu, rinv, 768, 128);
  qkv_spike<<<RR * 192 / 256, blk, 0, stream>>>(Yq, mu, rinv, qg, qb, kg, kb,
                                                vg, vb, qs_, ks_, vs_);

  // 4-6. attention: M = K^T V (exact int), o = 0.125 q@M -> exact 2-term f16
  attn_kv<<<dim3(32, 16), blk, 0, stream>>>(ks_, vs_, Mpart);
  attn_kv_reduce<<<512, blk, 0, stream>>>(Mpart, Mful);
  attn_qm<<<dim3(4, RR / 64), blk, 0, stream>>>(qs_, Mful, o2);

  // 7. x2 = x + o @ wo^T -> out   (MFMA, 3-term, K'=768)
  gemm_sp<64, 128, 2, 4, 0><<<dim3(2, 256), blk512, 0, stream>>>(
      o2, 512, wo2, 768, x, out, 256, nullptr, nullptr);

  // 8. h2 = LN2(x2) -> split f16
  ln_split<<<RR / 4, blk, 0, stream>>>(out, ln2g, ln2b, h2s);

  // 9-10. MLP1 (3-term, K'=768) + fused BN pass-1 + spike -> m1
  gemm_sp<128, 128, 2, 4, 1><<<dim3(8, 128), blk512, 0, stream>>>(
      h2s, 512, w12, 768, nullptr, Ym, 1024, p1, p2);
  bn_stats2<<<16, blk, 0, stream>>>(p1, p2, mu, rinv, 1024, 128);
  bn_spike_f16<<<16384, blk, 0, stream>>>(Ym, mu, rinv, b1g, b1b, m1, 1024);

  // 11-12. MLP2 (binary-exact A x 2-term W, K'=2048) + BN + spike-add
  gemm_sp<64, 128, 2, 4, 1><<<dim3(2, 256), blk512, 0, stream>>>(
      m1, 1024, w22, 2048, nullptr, Ym, 256, p1, p2);
  bn_stats2<<<4, blk, 0, stream>>>(p1, p2, mu, rinv, 256, 256);
  bn_spike_add<<<4096, blk, 0, stream>>>(Ym, mu, rinv, b2g, b2b, out, 256);
}